// Round 10
// baseline (336.630 us; speedup 1.0000x reference)
//
#include <hip/hip_runtime.h>
#include <stdint.h>

#define V_ 50257
#define D_ 1024
#define F_ 2048
#define B_ 64
#define E_ 512
#define ROWS_ (B_*E_)

typedef __attribute__((ext_vector_type(8))) short bf16x8;
typedef __attribute__((ext_vector_type(4))) float f32x4;

__device__ __forceinline__ unsigned rne1(float a) {
  unsigned u = __float_as_uint(a);
  return (u + 0x7FFFu + ((u >> 16) & 1u)) >> 16;
}

__device__ __forceinline__ float waveMax(float v) {
#pragma unroll
  for (int o = 32; o > 0; o >>= 1) v = fmaxf(v, __shfl_xor(v, o, 64));
  return v;
}
__device__ __forceinline__ float waveSum(float v) {
#pragma unroll
  for (int o = 32; o > 0; o >>= 1) v += __shfl_xor(v, o, 64);
  return v;
}

// ---------------- device bodies (round-8 proven versions) ----------------

__device__ __forceinline__ void ent_partial_body(int bid, const float* __restrict__ eh,
                                                 const void* __restrict__ mask,
                                                 float* __restrict__ part) {
  __shared__ int s_mode;
  const int tid = threadIdx.x;
  const uint32_t* mu = (const uint32_t*)mask;
  int f = 0;
  for (int i = tid; i < (ROWS_ / 4); i += 256) {
    uint32_t u = mu[i];
    if (u == 0x3F800000u) f |= 2;
    else if (u & 0xFFFFFF00u) f |= 1;
  }
  if (tid == 0) s_mode = 0;
  __syncthreads();
  if (f) atomicOr(&s_mode, f);
  __syncthreads();
  const int sm = s_mode;
  const int mode = (sm & 1) ? 1 : ((sm & 2) ? 2 : 0);

  float4 acc = make_float4(0.f, 0.f, 0.f, 0.f);
  const float4* eh4 = (const float4*)eh;
  for (int row = bid; row < ROWS_; row += 512) {
    bool on;
    if (mode == 1)      on = ((const unsigned char*)mask)[row] != 0;
    else if (mode == 2) on = ((const float*)mask)[row] != 0.f;
    else                on = ((const int*)mask)[row] != 0;
    if (on) {
      float4 v = eh4[(size_t)row * (D_ / 4) + tid];
      acc.x += v.x; acc.y += v.y; acc.z += v.z; acc.w += v.w;
    }
  }
  ((float4*)part)[(size_t)bid * (D_ / 4) + tid] = acc;
}

__device__ __forceinline__ void ent_reduce_body(int bid, const float* __restrict__ part,
                                                float* __restrict__ entsum) {
  int d = bid * 256 + threadIdx.x;
  float s0 = 0.f, s1 = 0.f, s2 = 0.f, s3 = 0.f;
  for (int i = 0; i < 512; i += 4) {
    s0 += part[(size_t)(i    ) * D_ + d];
    s1 += part[(size_t)(i + 1) * D_ + d];
    s2 += part[(size_t)(i + 2) * D_ + d];
    s3 += part[(size_t)(i + 3) * D_ + d];
  }
  entsum[d] = (s0 + s1) + (s2 + s3);
}

__device__ __forceinline__ void gemm64_body(int bx, int by, const float* __restrict__ X,
                                            const int* __restrict__ gatherIdx,
                                            const float* __restrict__ emb,
                                            const float* __restrict__ W,
                                            int K, int N, int KB, float* __restrict__ part) {
  const int l  = threadIdx.x & 63;
  const int rg = __builtin_amdgcn_readfirstlane((int)(threadIdx.x >> 6));
  const int c  = bx * 64 + l;
  const int k0 = by * KB;
  const int m0 = rg * 16;

  const float* Xp = gatherIdx ? emb : X;
  int rb[16];
#pragma unroll
  for (int r = 0; r < 16; ++r) {
    int m = m0 + r;
    rb[r] = gatherIdx ? gatherIdx[m] * K : m * K;
  }

  float acc[16];
#pragma unroll
  for (int r = 0; r < 16; ++r) acc[r] = 0.f;

  for (int k = k0; k < k0 + KB; k += 8) {
    float wv[8];
#pragma unroll
    for (int j = 0; j < 8; ++j) wv[j] = W[(size_t)(k + j) * N + c];
#pragma unroll
    for (int r = 0; r < 16; ++r) {
      float4 x0 = *(const float4*)&Xp[rb[r] + k];
      float4 x1 = *(const float4*)&Xp[rb[r] + k + 4];
      acc[r] = fmaf(x0.x, wv[0], acc[r]);
      acc[r] = fmaf(x0.y, wv[1], acc[r]);
      acc[r] = fmaf(x0.z, wv[2], acc[r]);
      acc[r] = fmaf(x0.w, wv[3], acc[r]);
      acc[r] = fmaf(x1.x, wv[4], acc[r]);
      acc[r] = fmaf(x1.y, wv[5], acc[r]);
      acc[r] = fmaf(x1.z, wv[6], acc[r]);
      acc[r] = fmaf(x1.w, wv[7], acc[r]);
    }
  }
  size_t base = (size_t)by * ((size_t)64 * N);
#pragma unroll
  for (int r = 0; r < 16; ++r) part[base + (size_t)(m0 + r) * N + c] = acc[r];
}

__device__ __forceinline__ void reduce_ep_body(int bid, const float* __restrict__ part,
                                               int nsplit, int MN, int N,
                                               const float* __restrict__ vecB,
                                               const float* __restrict__ addend,
                                               int mode, float* __restrict__ dst,
                                               unsigned short* __restrict__ dhi,
                                               unsigned short* __restrict__ dlo) {
  int idx = bid * 256 + threadIdx.x;
  if (idx >= MN) return;
  float s = 0.f;
  for (int i = 0; i < nsplit; ++i) s += part[(size_t)i * MN + idx];
  int c = idx & (N - 1);
  if (mode == 1)      { s += vecB[c]; s = s > 0.f ? s : 0.f; dst[idx] = s; }
  else if (mode == 2) { s += vecB[c]; dst[idx] = s; }
  else if (mode == 3) { s *= vecB[c]; dst[idx] = s; }
  else {
    s += addend[idx];
    unsigned hi = rne1(s);
    float hif = __uint_as_float(hi << 16);
    dhi[idx] = (unsigned short)hi;
    dlo[idx] = (unsigned short)rne1(s - hif);
  }
}

// ---------------- fused phase kernels (round-8 proven) ----------------
__global__ void k_p1(const float* __restrict__ eh, const void* __restrict__ mask,
                     float* __restrict__ entpart, const int* __restrict__ ques,
                     const float* __restrict__ emb, const float* __restrict__ W1,
                     float* __restrict__ gpart) {
  int bid = blockIdx.x;
  if (bid < 512) ent_partial_body(bid, eh, mask, entpart);
  else {
    int b2 = bid - 512;
    gemm64_body(b2 & 31, b2 >> 5, nullptr, ques, emb, W1, 1024, 2048, 64, gpart);
  }
}

__global__ void k_p2(const float* __restrict__ entpart, float* __restrict__ entsum,
                     const float* __restrict__ gpart, const float* __restrict__ b1,
                     float* __restrict__ hbuf) {
  int bid = blockIdx.x;
  if (bid < 4) ent_reduce_body(bid, entpart, entsum);
  else reduce_ep_body(bid - 4, gpart, 16, 64 * 2048, 2048, b1, nullptr, 1, hbuf, nullptr, nullptr);
}

__global__ void k_gemm64(const float* __restrict__ X, const float* __restrict__ W,
                         int K, int N, int KB, float* __restrict__ part) {
  gemm64_body(blockIdx.x, blockIdx.y, X, nullptr, nullptr, W, K, N, KB, part);
}

__global__ void k_reduce_ep(const float* __restrict__ part, int nsplit, int MN, int N,
                            const float* __restrict__ vecB, const float* __restrict__ addend,
                            int mode, float* __restrict__ dst,
                            unsigned short* __restrict__ dhi, unsigned short* __restrict__ dlo) {
  reduce_ep_body(blockIdx.x, part, nsplit, MN, N, vecB, addend, mode, dst, dhi, dlo);
}

// ---------------- big GEMM: logits = Z[64,1024] @ Ws[1024,V] + bs, split-bf16 MFMA -------
// 8-wave blocks, split-K across wave halves. Waves 0-3: K [0,512); waves 4-7: K [512,1024).
// Each half: round-8's proven double-buffered LDS staging (global_load_lds size=4,
// __syncthreads drain) on its own 2x8KB buffers -> 16 KB staged per block per barrier
// (2x round 8) and 75% occupancy (24 waves/CU at ~3 blocks resident). Per-iter order
// unchanged from round 8: z-frags first (their vmcnt wait leaves staging in flight),
// stage next tile, ds_read+cvt+MFMA, sync. Epilogue: half-1 acc -> LDS (reusing staging
// space after final sync), half-0 adds + bias + stores. No extra HBM traffic or ws.
__global__ __launch_bounds__(512, 6) void k_gemm_big(const unsigned short* __restrict__ zhi,
                                                     const unsigned short* __restrict__ zlo,
                                                     const float* __restrict__ Ws,
                                                     const float* __restrict__ bs,
                                                     float* __restrict__ logits) {
  __shared__ float lds[2][2][32 * 64];   // [K-half][buf][row*64+col] : 32 KB
  const int t    = threadIdx.x;
  const int l    = t & 63;
  const int w    = t >> 6;               // 0..7
  const int h    = w >> 2;               // K-half
  const int ww   = w & 3;                // col-group wave within half
  const int col  = l & 15;
  const int g    = l >> 4;               // k-chunk g*8..g*8+7 within a 32-row tile
  const int c0   = blockIdx.x * 64;
  const int c    = c0 + ww * 16 + col;
  const int kbase = h * 512;

  int scol = c0 + l;
  if (scol > V_ - 1) scol = V_ - 1;

  unsigned aoff[4];
#pragma unroll
  for (int m = 0; m < 4; ++m) aoff[m] = (unsigned)((m * 16 + col) * D_ + g * 8);

  f32x4 acc[4];
#pragma unroll
  for (int m = 0; m < 4; ++m) acc[m] = (f32x4){0.f, 0.f, 0.f, 0.f};

  // prologue: stage tile 0 of this half. wave ww stages rows i*4+ww (256B coalesced).
#pragma unroll
  for (int i = 0; i < 8; ++i) {
    const int r = i * 4 + ww;
    __builtin_amdgcn_global_load_lds(
        (const __attribute__((address_space(1))) void*)(Ws + (size_t)(kbase + r) * V_ + scol),
        (__attribute__((address_space(3))) void*)&lds[h][0][r * 64],
        4, 0, 0);
  }
  __syncthreads();

  for (int it = 0; it < 16; ++it) {
    const int buf = it & 1;
    const int k0  = kbase + it * 32;

    // A-fragments first: their vmcnt wait (before MFMA) leaves staging DMA in flight.
    bf16x8 ah[4], al[4];
#pragma unroll
    for (int m = 0; m < 4; ++m) {
      ah[m] = *(const bf16x8*)(zhi + aoff[m] + k0);
      al[m] = *(const bf16x8*)(zlo + aoff[m] + k0);
    }

    if (it + 1 < 16) {
      const float* wb = Ws + (size_t)(k0 + 32) * V_ + scol;
#pragma unroll
      for (int i = 0; i < 8; ++i) {
        const int r = i * 4 + ww;
        __builtin_amdgcn_global_load_lds(
            (const __attribute__((address_space(1))) void*)(wb + (size_t)r * V_),
            (__attribute__((address_space(3))) void*)&lds[h][buf ^ 1][r * 64],
            4, 0, 0);
      }
    }

    float f[8];
#pragma unroll
    for (int j = 0; j < 8; ++j) f[j] = lds[h][buf][(g * 8 + j) * 64 + ww * 16 + col];

    union { bf16x8 v; unsigned u[4]; } bh, bl;
#pragma unroll
    for (int j = 0; j < 4; ++j) {
      unsigned h0 = rne1(f[2 * j]);
      unsigned h1 = rne1(f[2 * j + 1]);
      float h0f = __uint_as_float(h0 << 16);
      float h1f = __uint_as_float(h1 << 16);
      bh.u[j] = h0 | (h1 << 16);
      bl.u[j] = rne1(f[2 * j] - h0f) | (rne1(f[2 * j + 1] - h1f) << 16);
    }
#pragma unroll
    for (int m = 0; m < 4; ++m) acc[m] = __builtin_amdgcn_mfma_f32_16x16x32_bf16(ah[m], bh.v, acc[m], 0, 0, 0);
#pragma unroll
    for (int m = 0; m < 4; ++m) acc[m] = __builtin_amdgcn_mfma_f32_16x16x32_bf16(ah[m], bl.v, acc[m], 0, 0, 0);
#pragma unroll
    for (int m = 0; m < 4; ++m) acc[m] = __builtin_amdgcn_mfma_f32_16x16x32_bf16(al[m], bh.v, acc[m], 0, 0, 0);

    __syncthreads();
  }

  // cross-half reduction: reuse staging LDS (all staging reads retired at last sync).
  float* red = &lds[0][0][0];   // 64 rows x 64 cols f32 = 16 KB
  if (h == 1) {
#pragma unroll
    for (int m = 0; m < 4; ++m)
#pragma unroll
      for (int i = 0; i < 4; ++i)
        red[(m * 16 + g * 4 + i) * 64 + ww * 16 + col] = acc[m][i];
  }
  __syncthreads();
  if (h == 0 && c < V_) {
    float bias = bs[c];
#pragma unroll
    for (int m = 0; m < 4; ++m)
#pragma unroll
      for (int i = 0; i < 4; ++i)
        logits[(size_t)(m * 16 + g * 4 + i) * V_ + c]
            = acc[m][i] + red[(m * 16 + g * 4 + i) * 64 + ww * 16 + col] + bias;
  }
}

// ---------------- softmax over rows of logits [64, V], two-pass 256-block ----------------
#define SM_CHUNK 12565  // 4 * 12565 >= V_

__global__ void k_softmax1(const float* __restrict__ logits, float2* __restrict__ stats) {
  __shared__ float smx[4], ssum[4];
  const int r = blockIdx.x >> 2, q = blockIdx.x & 3;
  const int beg = q * SM_CHUNK;
  const int end = (beg + SM_CHUNK < V_) ? beg + SM_CHUNK : V_;
  const float* row = logits + (size_t)r * V_;

  float mx = -3.4e38f;
  for (int i = beg + threadIdx.x; i < end; i += 256) mx = fmaxf(mx, row[i]);
  mx = waveMax(mx);
  if ((threadIdx.x & 63) == 0) smx[threadIdx.x >> 6] = mx;
  __syncthreads();
  mx = fmaxf(fmaxf(smx[0], smx[1]), fmaxf(smx[2], smx[3]));

  float s = 0.f;
  for (int i = beg + threadIdx.x; i < end; i += 256) s += __expf(row[i] - mx);
  s = waveSum(s);
  if ((threadIdx.x & 63) == 0) ssum[threadIdx.x >> 6] = s;
  __syncthreads();
  s = (ssum[0] + ssum[1]) + (ssum[2] + ssum[3]);

  if (threadIdx.x == 0) stats[blockIdx.x] = make_float2(mx, s);
}

__global__ void k_softmax2(const float* __restrict__ logits, const float2* __restrict__ stats,
                           float* __restrict__ out) {
  const int r = blockIdx.x >> 2, q = blockIdx.x & 3;
  float2 s0 = stats[r * 4 + 0], s1 = stats[r * 4 + 1];
  float2 s2 = stats[r * 4 + 2], s3 = stats[r * 4 + 3];
  float M = fmaxf(fmaxf(s0.x, s1.x), fmaxf(s2.x, s3.x));
  float S = s0.y * __expf(s0.x - M) + s1.y * __expf(s1.x - M)
          + s2.y * __expf(s2.x - M) + s3.y * __expf(s3.x - M);
  float inv = 1.f / S;
  const int beg = q * SM_CHUNK;
  const int end = (beg + SM_CHUNK < V_) ? beg + SM_CHUNK : V_;
  const float* row = logits + (size_t)r * V_;
  float* orow = out + (size_t)r * V_;
  for (int i = beg + threadIdx.x; i < end; i += 256) orow[i] = __expf(row[i] - M) * inv;
}

// ---------------- launch ----------------
extern "C" void kernel_launch(void* const* d_in, const int* in_sizes, int n_in,
                              void* d_out, int out_size, void* d_ws, size_t ws_size,
                              hipStream_t stream) {
  const float* eh   = (const float*)d_in[0];
  const int*   ques = (const int*)d_in[1];
  const void*  mask = d_in[2];
  const float* emb  = (const float*)d_in[3];
  const float* W1   = (const float*)d_in[4];
  const float* b1   = (const float*)d_in[5];
  const float* W2   = (const float*)d_in[6];
  const float* b2   = (const float*)d_in[7];
  const float* A    = (const float*)d_in[8];
  const float* H    = (const float*)d_in[9];
  const float* Ws   = (const float*)d_in[10];
  const float* bs   = (const float*)d_in[11];
  float* out = (float*)d_out;
  char* ws = (char*)d_ws;

  // ws layout (bytes). gpart aliases logits (temporally disjoint).  [round-8 proven]
  float*          logits  = (float*)(ws + 0);           // 12,865,792
  float*          gpart   = (float*)(ws + 0);           // max 8,388,608 (aliased)
  float*          entpart = (float*)(ws + 12866048);    // 2,097,152
  float*          entsum  = (float*)(ws + 14963200);    // 4,096
  float*          hbuf    = (float*)(ws + 14967296);    // 524,288
  float*          qbuf    = (float*)(ws + 15491584);    // 262,144
  float*          ubuf    = (float*)(ws + 15753728);    // 262,144
  unsigned short* zhi16   = (unsigned short*)(ws + 16015872);  // 131,072
  unsigned short* zlo16   = (unsigned short*)(ws + 16146944);  // 131,072
  float2*         stats   = (float2*)(ws + 16278016);   // 2,048

  // P1: ent_partial (512 blocks) || h-gemm partials (512 blocks)
  k_p1<<<1024, 256, 0, stream>>>(eh, mask, entpart, ques, emb, W1, gpart);
  // P2: ent_reduce (4) || h = relu(.+b1) (512)
  k_p2<<<516, 256, 0, stream>>>(entpart, entsum, gpart, b1, hbuf);

  // P3/P4: q = h @ W2 + b2                 [64,1024], K=2048, split 32
  k_gemm64<<<dim3(16, 32), 256, 0, stream>>>(hbuf, W2, 2048, 1024, 64, gpart);
  k_reduce_ep<<<256, 256, 0, stream>>>(gpart, 32, 64 * 1024, 1024, b2, nullptr, 2, qbuf, nullptr, nullptr);

  // P5/P6: u = (q @ A) * ent_sum           [64,1024], split 16
  k_gemm64<<<dim3(16, 16), 256, 0, stream>>>(qbuf, A, 1024, 1024, 64, gpart);
  k_reduce_ep<<<256, 256, 0, stream>>>(gpart, 16, 64 * 1024, 1024, entsum, nullptr, 3, ubuf, nullptr, nullptr);

  // P7/P8: z = q + u @ H (-> bf16 hi/lo)   [64,1024], split 16
  k_gemm64<<<dim3(16, 16), 256, 0, stream>>>(ubuf, H, 1024, 1024, 64, gpart);
  k_reduce_ep<<<256, 256, 0, stream>>>(gpart, 16, 64 * 1024, 1024, nullptr, qbuf, 4, nullptr, zhi16, zlo16);

  // P9: logits = z @ Ws + bs               [64,V], 8-wave split-K, LDS-staged Ws
  k_gemm_big<<<786, 512, 0, stream>>>(zhi16, zlo16, Ws, bs, logits);

  // P10/P11: softmax two-pass
  k_softmax1<<<256, 256, 0, stream>>>(logits, stats);
  k_softmax2<<<256, 256, 0, stream>>>(logits, stats, out);

  (void)in_sizes; (void)n_in; (void)out_size; (void)ws_size;
}

// Round 11
// 274.061 us; speedup vs baseline: 1.2283x; 1.2283x over previous
//
#include <hip/hip_runtime.h>
#include <stdint.h>

#define V_ 50257
#define D_ 1024
#define F_ 2048
#define B_ 64
#define E_ 512
#define ROWS_ (B_*E_)

typedef __attribute__((ext_vector_type(8))) short bf16x8;
typedef __attribute__((ext_vector_type(4))) float f32x4;

__device__ __forceinline__ unsigned rne1(float a) {
  unsigned u = __float_as_uint(a);
  return (u + 0x7FFFu + ((u >> 16) & 1u)) >> 16;
}

__device__ __forceinline__ float waveMax(float v) {
#pragma unroll
  for (int o = 32; o > 0; o >>= 1) v = fmaxf(v, __shfl_xor(v, o, 64));
  return v;
}
__device__ __forceinline__ float waveSum(float v) {
#pragma unroll
  for (int o = 32; o > 0; o >>= 1) v += __shfl_xor(v, o, 64);
  return v;
}

// ---------------- device bodies (round-8 proven versions) ----------------

__device__ __forceinline__ void ent_partial_body(int bid, const float* __restrict__ eh,
                                                 const void* __restrict__ mask,
                                                 float* __restrict__ part) {
  __shared__ int s_mode;
  const int tid = threadIdx.x;
  const uint32_t* mu = (const uint32_t*)mask;
  int f = 0;
  for (int i = tid; i < (ROWS_ / 4); i += 256) {
    uint32_t u = mu[i];
    if (u == 0x3F800000u) f |= 2;
    else if (u & 0xFFFFFF00u) f |= 1;
  }
  if (tid == 0) s_mode = 0;
  __syncthreads();
  if (f) atomicOr(&s_mode, f);
  __syncthreads();
  const int sm = s_mode;
  const int mode = (sm & 1) ? 1 : ((sm & 2) ? 2 : 0);

  float4 acc = make_float4(0.f, 0.f, 0.f, 0.f);
  const float4* eh4 = (const float4*)eh;
  for (int row = bid; row < ROWS_; row += 512) {
    bool on;
    if (mode == 1)      on = ((const unsigned char*)mask)[row] != 0;
    else if (mode == 2) on = ((const float*)mask)[row] != 0.f;
    else                on = ((const int*)mask)[row] != 0;
    if (on) {
      float4 v = eh4[(size_t)row * (D_ / 4) + tid];
      acc.x += v.x; acc.y += v.y; acc.z += v.z; acc.w += v.w;
    }
  }
  ((float4*)part)[(size_t)bid * (D_ / 4) + tid] = acc;
}

__device__ __forceinline__ void ent_reduce_body(int bid, const float* __restrict__ part,
                                                float* __restrict__ entsum) {
  int d = bid * 256 + threadIdx.x;
  float s0 = 0.f, s1 = 0.f, s2 = 0.f, s3 = 0.f;
  for (int i = 0; i < 512; i += 4) {
    s0 += part[(size_t)(i    ) * D_ + d];
    s1 += part[(size_t)(i + 1) * D_ + d];
    s2 += part[(size_t)(i + 2) * D_ + d];
    s3 += part[(size_t)(i + 3) * D_ + d];
  }
  entsum[d] = (s0 + s1) + (s2 + s3);
}

__device__ __forceinline__ void gemm64_body(int bx, int by, const float* __restrict__ X,
                                            const int* __restrict__ gatherIdx,
                                            const float* __restrict__ emb,
                                            const float* __restrict__ W,
                                            int K, int N, int KB, float* __restrict__ part) {
  const int l  = threadIdx.x & 63;
  const int rg = __builtin_amdgcn_readfirstlane((int)(threadIdx.x >> 6));
  const int c  = bx * 64 + l;
  const int k0 = by * KB;
  const int m0 = rg * 16;

  const float* Xp = gatherIdx ? emb : X;
  int rb[16];
#pragma unroll
  for (int r = 0; r < 16; ++r) {
    int m = m0 + r;
    rb[r] = gatherIdx ? gatherIdx[m] * K : m * K;
  }

  float acc[16];
#pragma unroll
  for (int r = 0; r < 16; ++r) acc[r] = 0.f;

  for (int k = k0; k < k0 + KB; k += 8) {
    float wv[8];
#pragma unroll
    for (int j = 0; j < 8; ++j) wv[j] = W[(size_t)(k + j) * N + c];
#pragma unroll
    for (int r = 0; r < 16; ++r) {
      float4 x0 = *(const float4*)&Xp[rb[r] + k];
      float4 x1 = *(const float4*)&Xp[rb[r] + k + 4];
      acc[r] = fmaf(x0.x, wv[0], acc[r]);
      acc[r] = fmaf(x0.y, wv[1], acc[r]);
      acc[r] = fmaf(x0.z, wv[2], acc[r]);
      acc[r] = fmaf(x0.w, wv[3], acc[r]);
      acc[r] = fmaf(x1.x, wv[4], acc[r]);
      acc[r] = fmaf(x1.y, wv[5], acc[r]);
      acc[r] = fmaf(x1.z, wv[6], acc[r]);
      acc[r] = fmaf(x1.w, wv[7], acc[r]);
    }
  }
  size_t base = (size_t)by * ((size_t)64 * N);
#pragma unroll
  for (int r = 0; r < 16; ++r) part[base + (size_t)(m0 + r) * N + c] = acc[r];
}

__device__ __forceinline__ void reduce_ep_body(int bid, const float* __restrict__ part,
                                               int nsplit, int MN, int N,
                                               const float* __restrict__ vecB,
                                               const float* __restrict__ addend,
                                               int mode, float* __restrict__ dst,
                                               unsigned short* __restrict__ dhi,
                                               unsigned short* __restrict__ dlo) {
  int idx = bid * 256 + threadIdx.x;
  if (idx >= MN) return;
  float s = 0.f;
  for (int i = 0; i < nsplit; ++i) s += part[(size_t)i * MN + idx];
  int c = idx & (N - 1);
  if (mode == 1)      { s += vecB[c]; s = s > 0.f ? s : 0.f; dst[idx] = s; }
  else if (mode == 2) { s += vecB[c]; dst[idx] = s; }
  else if (mode == 3) { s *= vecB[c]; dst[idx] = s; }
  else {
    s += addend[idx];
    unsigned hi = rne1(s);
    float hif = __uint_as_float(hi << 16);
    dhi[idx] = (unsigned short)hi;
    dlo[idx] = (unsigned short)rne1(s - hif);
  }
}

// ---------------- fused phase kernels (round-8 proven) ----------------
__global__ void k_p1(const float* __restrict__ eh, const void* __restrict__ mask,
                     float* __restrict__ entpart, const int* __restrict__ ques,
                     const float* __restrict__ emb, const float* __restrict__ W1,
                     float* __restrict__ gpart) {
  int bid = blockIdx.x;
  if (bid < 512) ent_partial_body(bid, eh, mask, entpart);
  else {
    int b2 = bid - 512;
    gemm64_body(b2 & 31, b2 >> 5, nullptr, ques, emb, W1, 1024, 2048, 64, gpart);
  }
}

__global__ void k_p2(const float* __restrict__ entpart, float* __restrict__ entsum,
                     const float* __restrict__ gpart, const float* __restrict__ b1,
                     float* __restrict__ hbuf) {
  int bid = blockIdx.x;
  if (bid < 4) ent_reduce_body(bid, entpart, entsum);
  else reduce_ep_body(bid - 4, gpart, 16, 64 * 2048, 2048, b1, nullptr, 1, hbuf, nullptr, nullptr);
}

__global__ void k_gemm64(const float* __restrict__ X, const float* __restrict__ W,
                         int K, int N, int KB, float* __restrict__ part) {
  gemm64_body(blockIdx.x, blockIdx.y, X, nullptr, nullptr, W, K, N, KB, part);
}

__global__ void k_reduce_ep(const float* __restrict__ part, int nsplit, int MN, int N,
                            const float* __restrict__ vecB, const float* __restrict__ addend,
                            int mode, float* __restrict__ dst,
                            unsigned short* __restrict__ dhi, unsigned short* __restrict__ dlo) {
  reduce_ep_body(blockIdx.x, part, nsplit, MN, N, vecB, addend, mode, dst, dhi, dlo);
}

// ---------------- big GEMM: logits = Z[64,1024] @ Ws[1024,V] + bs, split-bf16 MFMA -------
// DRAM-locality variant of the proven round-8 kernel: block column tile widened 64 -> 256
// f32 so each k-row read is 1 KB contiguous (4x DRAM burst locality; theory: the ~1.0 TB/s
// plateau of rounds 3-10 is 256-B-chunk page-miss inefficiency, evidenced by the linear
// spill stream in round 6 adding +0.8 TB/s on top, and by k_p1's 4-KB-row entity stream
// never appearing in top-5). Grid 197 blocks, 4 waves; wave owns 64 cols = 4 N-tiles x
// 4 M-tiles (acc 64 VGPR). LDS tile 32 x 256 f32, row stride 257 (pad kills the 4-way
// g-group bank conflict), double-buffered = 65.8 KB -> 2 blocks/CU. Same stage/drain
// discipline as round 8: z-frags first, stage next tile (global_load_lds size=4, per-lane
// clamped source, per-row-chunk uniform LDS dest), compute, __syncthreads.
__global__ __launch_bounds__(256) void k_gemm_big(const unsigned short* __restrict__ zhi,
                                                  const unsigned short* __restrict__ zlo,
                                                  const float* __restrict__ Ws,
                                                  const float* __restrict__ bs,
                                                  float* __restrict__ logits) {
  __shared__ float lds[2][32 * 257];   // 65,792 B
  const int t   = threadIdx.x;
  const int l   = t & 63;
  const int w   = t >> 6;              // col-quarter 0..3
  const int col = l & 15;
  const int g   = l >> 4;              // k-chunk g*8..g*8+7
  const int c0  = blockIdx.x * 256;

  int scol[4];
#pragma unroll
  for (int j = 0; j < 4; ++j) {
    int s = c0 + j * 64 + l;
    scol[j] = s < V_ ? s : V_ - 1;
  }

  unsigned aoff[4];
#pragma unroll
  for (int m = 0; m < 4; ++m) aoff[m] = (unsigned)((m * 16 + col) * D_ + g * 8);

  f32x4 acc[4][4];  // [n][m], fully unrolled indexing only
#pragma unroll
  for (int n = 0; n < 4; ++n)
#pragma unroll
    for (int m = 0; m < 4; ++m) acc[n][m] = (f32x4){0.f, 0.f, 0.f, 0.f};

  // prologue: stage tile 0. wave w stages rows w*8..w*8+7, 4 chunks (256 B) per row.
#pragma unroll
  for (int i = 0; i < 8; ++i) {
    const int r = w * 8 + i;
#pragma unroll
    for (int j = 0; j < 4; ++j) {
      __builtin_amdgcn_global_load_lds(
          (const __attribute__((address_space(1))) void*)(Ws + (size_t)r * V_ + scol[j]),
          (__attribute__((address_space(3))) void*)&lds[0][r * 257 + j * 64],
          4, 0, 0);
    }
  }
  __syncthreads();

  for (int it = 0; it < 32; ++it) {
    const int buf = it & 1;
    const int k0  = it * 32;

    // A-fragments first: their counted vmcnt wait leaves staging DMA in flight.
    bf16x8 ah[4], al[4];
#pragma unroll
    for (int m = 0; m < 4; ++m) {
      ah[m] = *(const bf16x8*)(zhi + aoff[m] + k0);
      al[m] = *(const bf16x8*)(zlo + aoff[m] + k0);
    }

    if (it + 1 < 32) {
      const float* wb = Ws + (size_t)(k0 + 32) * V_;
#pragma unroll
      for (int i = 0; i < 8; ++i) {
        const int r = w * 8 + i;
#pragma unroll
        for (int j = 0; j < 4; ++j) {
          __builtin_amdgcn_global_load_lds(
              (const __attribute__((address_space(1))) void*)(wb + (size_t)r * V_ + scol[j]),
              (__attribute__((address_space(3))) void*)&lds[buf ^ 1][r * 257 + j * 64],
              4, 0, 0);
        }
      }
    }

#pragma unroll
    for (int n = 0; n < 4; ++n) {
      float f[8];
#pragma unroll
      for (int j = 0; j < 8; ++j)
        f[j] = lds[buf][(g * 8 + j) * 257 + w * 64 + n * 16 + col];

      union { bf16x8 v; unsigned u[4]; } bh, bl;
#pragma unroll
      for (int j = 0; j < 4; ++j) {
        unsigned h0 = rne1(f[2 * j]);
        unsigned h1 = rne1(f[2 * j + 1]);
        float h0f = __uint_as_float(h0 << 16);
        float h1f = __uint_as_float(h1 << 16);
        bh.u[j] = h0 | (h1 << 16);
        bl.u[j] = rne1(f[2 * j] - h0f) | (rne1(f[2 * j + 1] - h1f) << 16);
      }
#pragma unroll
      for (int m = 0; m < 4; ++m) acc[n][m] = __builtin_amdgcn_mfma_f32_16x16x32_bf16(ah[m], bh.v, acc[n][m], 0, 0, 0);
#pragma unroll
      for (int m = 0; m < 4; ++m) acc[n][m] = __builtin_amdgcn_mfma_f32_16x16x32_bf16(ah[m], bl.v, acc[n][m], 0, 0, 0);
#pragma unroll
      for (int m = 0; m < 4; ++m) acc[n][m] = __builtin_amdgcn_mfma_f32_16x16x32_bf16(al[m], bh.v, acc[n][m], 0, 0, 0);
    }

    __syncthreads();
  }

#pragma unroll
  for (int n = 0; n < 4; ++n) {
    const int c = c0 + w * 64 + n * 16 + col;
    if (c < V_) {
      float bias = bs[c];
#pragma unroll
      for (int m = 0; m < 4; ++m)
#pragma unroll
        for (int i = 0; i < 4; ++i)
          logits[(size_t)(m * 16 + g * 4 + i) * V_ + c] = acc[n][m][i] + bias;
    }
  }
}

// ---------------- softmax over rows of logits [64, V], two-pass 256-block ----------------
#define SM_CHUNK 12565  // 4 * 12565 >= V_

__global__ void k_softmax1(const float* __restrict__ logits, float2* __restrict__ stats) {
  __shared__ float smx[4], ssum[4];
  const int r = blockIdx.x >> 2, q = blockIdx.x & 3;
  const int beg = q * SM_CHUNK;
  const int end = (beg + SM_CHUNK < V_) ? beg + SM_CHUNK : V_;
  const float* row = logits + (size_t)r * V_;

  float mx = -3.4e38f;
  for (int i = beg + threadIdx.x; i < end; i += 256) mx = fmaxf(mx, row[i]);
  mx = waveMax(mx);
  if ((threadIdx.x & 63) == 0) smx[threadIdx.x >> 6] = mx;
  __syncthreads();
  mx = fmaxf(fmaxf(smx[0], smx[1]), fmaxf(smx[2], smx[3]));

  float s = 0.f;
  for (int i = beg + threadIdx.x; i < end; i += 256) s += __expf(row[i] - mx);
  s = waveSum(s);
  if ((threadIdx.x & 63) == 0) ssum[threadIdx.x >> 6] = s;
  __syncthreads();
  s = (ssum[0] + ssum[1]) + (ssum[2] + ssum[3]);

  if (threadIdx.x == 0) stats[blockIdx.x] = make_float2(mx, s);
}

__global__ void k_softmax2(const float* __restrict__ logits, const float2* __restrict__ stats,
                           float* __restrict__ out) {
  const int r = blockIdx.x >> 2, q = blockIdx.x & 3;
  float2 s0 = stats[r * 4 + 0], s1 = stats[r * 4 + 1];
  float2 s2 = stats[r * 4 + 2], s3 = stats[r * 4 + 3];
  float M = fmaxf(fmaxf(s0.x, s1.x), fmaxf(s2.x, s3.x));
  float S = s0.y * __expf(s0.x - M) + s1.y * __expf(s1.x - M)
          + s2.y * __expf(s2.x - M) + s3.y * __expf(s3.x - M);
  float inv = 1.f / S;
  const int beg = q * SM_CHUNK;
  const int end = (beg + SM_CHUNK < V_) ? beg + SM_CHUNK : V_;
  const float* row = logits + (size_t)r * V_;
  float* orow = out + (size_t)r * V_;
  for (int i = beg + threadIdx.x; i < end; i += 256) orow[i] = __expf(row[i] - M) * inv;
}

// ---------------- launch ----------------
extern "C" void kernel_launch(void* const* d_in, const int* in_sizes, int n_in,
                              void* d_out, int out_size, void* d_ws, size_t ws_size,
                              hipStream_t stream) {
  const float* eh   = (const float*)d_in[0];
  const int*   ques = (const int*)d_in[1];
  const void*  mask = d_in[2];
  const float* emb  = (const float*)d_in[3];
  const float* W1   = (const float*)d_in[4];
  const float* b1   = (const float*)d_in[5];
  const float* W2   = (const float*)d_in[6];
  const float* b2   = (const float*)d_in[7];
  const float* A    = (const float*)d_in[8];
  const float* H    = (const float*)d_in[9];
  const float* Ws   = (const float*)d_in[10];
  const float* bs   = (const float*)d_in[11];
  float* out = (float*)d_out;
  char* ws = (char*)d_ws;

  // ws layout (bytes). gpart aliases logits (temporally disjoint).  [round-8 proven]
  float*          logits  = (float*)(ws + 0);           // 12,865,792
  float*          gpart   = (float*)(ws + 0);           // max 8,388,608 (aliased)
  float*          entpart = (float*)(ws + 12866048);    // 2,097,152
  float*          entsum  = (float*)(ws + 14963200);    // 4,096
  float*          hbuf    = (float*)(ws + 14967296);    // 524,288
  float*          qbuf    = (float*)(ws + 15491584);    // 262,144
  float*          ubuf    = (float*)(ws + 15753728);    // 262,144
  unsigned short* zhi16   = (unsigned short*)(ws + 16015872);  // 131,072
  unsigned short* zlo16   = (unsigned short*)(ws + 16146944);  // 131,072
  float2*         stats   = (float2*)(ws + 16278016);   // 2,048

  // P1: ent_partial (512 blocks) || h-gemm partials (512 blocks)
  k_p1<<<1024, 256, 0, stream>>>(eh, mask, entpart, ques, emb, W1, gpart);
  // P2: ent_reduce (4) || h = relu(.+b1) (512)
  k_p2<<<516, 256, 0, stream>>>(entpart, entsum, gpart, b1, hbuf);

  // P3/P4: q = h @ W2 + b2                 [64,1024], K=2048, split 32
  k_gemm64<<<dim3(16, 32), 256, 0, stream>>>(hbuf, W2, 2048, 1024, 64, gpart);
  k_reduce_ep<<<256, 256, 0, stream>>>(gpart, 32, 64 * 1024, 1024, b2, nullptr, 2, qbuf, nullptr, nullptr);

  // P5/P6: u = (q @ A) * ent_sum           [64,1024], split 16
  k_gemm64<<<dim3(16, 16), 256, 0, stream>>>(qbuf, A, 1024, 1024, 64, gpart);
  k_reduce_ep<<<256, 256, 0, stream>>>(gpart, 16, 64 * 1024, 1024, entsum, nullptr, 3, ubuf, nullptr, nullptr);

  // P7/P8: z = q + u @ H (-> bf16 hi/lo)   [64,1024], split 16
  k_gemm64<<<dim3(16, 16), 256, 0, stream>>>(ubuf, H, 1024, 1024, 64, gpart);
  k_reduce_ep<<<256, 256, 0, stream>>>(gpart, 16, 64 * 1024, 1024, nullptr, qbuf, 4, nullptr, zhi16, zlo16);

  // P9: logits = z @ Ws + bs               [64,V], 256-col tiles, LDS-staged Ws
  k_gemm_big<<<197, 256, 0, stream>>>(zhi16, zlo16, Ws, bs, logits);

  // P10/P11: softmax two-pass
  k_softmax1<<<256, 256, 0, stream>>>(logits, stats);
  k_softmax2<<<256, 256, 0, stream>>>(logits, stats, out);

  (void)in_sizes; (void)n_in; (void)out_size; (void)ws_size;
}

// Round 12
// 273.942 us; speedup vs baseline: 1.2288x; 1.0004x over previous
//
#include <hip/hip_runtime.h>
#include <stdint.h>

#define V_ 50257
#define D_ 1024
#define F_ 2048
#define B_ 64
#define E_ 512
#define ROWS_ (B_*E_)

typedef __attribute__((ext_vector_type(8))) short bf16x8;
typedef __attribute__((ext_vector_type(4))) float f32x4;

__device__ __forceinline__ unsigned rne1(float a) {
  unsigned u = __float_as_uint(a);
  return (u + 0x7FFFu + ((u >> 16) & 1u)) >> 16;
}

__device__ __forceinline__ float waveMax(float v) {
#pragma unroll
  for (int o = 32; o > 0; o >>= 1) v = fmaxf(v, __shfl_xor(v, o, 64));
  return v;
}
__device__ __forceinline__ float waveSum(float v) {
#pragma unroll
  for (int o = 32; o > 0; o >>= 1) v += __shfl_xor(v, o, 64);
  return v;
}

// ---------------- device bodies (round-8 proven versions) ----------------

__device__ __forceinline__ void ent_partial_body(int bid, const float* __restrict__ eh,
                                                 const void* __restrict__ mask,
                                                 float* __restrict__ part) {
  __shared__ int s_mode;
  const int tid = threadIdx.x;
  const uint32_t* mu = (const uint32_t*)mask;
  int f = 0;
  for (int i = tid; i < (ROWS_ / 4); i += 256) {
    uint32_t u = mu[i];
    if (u == 0x3F800000u) f |= 2;
    else if (u & 0xFFFFFF00u) f |= 1;
  }
  if (tid == 0) s_mode = 0;
  __syncthreads();
  if (f) atomicOr(&s_mode, f);
  __syncthreads();
  const int sm = s_mode;
  const int mode = (sm & 1) ? 1 : ((sm & 2) ? 2 : 0);

  float4 acc = make_float4(0.f, 0.f, 0.f, 0.f);
  const float4* eh4 = (const float4*)eh;
  for (int row = bid; row < ROWS_; row += 512) {
    bool on;
    if (mode == 1)      on = ((const unsigned char*)mask)[row] != 0;
    else if (mode == 2) on = ((const float*)mask)[row] != 0.f;
    else                on = ((const int*)mask)[row] != 0;
    if (on) {
      float4 v = eh4[(size_t)row * (D_ / 4) + tid];
      acc.x += v.x; acc.y += v.y; acc.z += v.z; acc.w += v.w;
    }
  }
  ((float4*)part)[(size_t)bid * (D_ / 4) + tid] = acc;
}

__device__ __forceinline__ void ent_reduce_body(int bid, const float* __restrict__ part,
                                                float* __restrict__ entsum) {
  int d = bid * 256 + threadIdx.x;
  float s0 = 0.f, s1 = 0.f, s2 = 0.f, s3 = 0.f;
  for (int i = 0; i < 512; i += 4) {
    s0 += part[(size_t)(i    ) * D_ + d];
    s1 += part[(size_t)(i + 1) * D_ + d];
    s2 += part[(size_t)(i + 2) * D_ + d];
    s3 += part[(size_t)(i + 3) * D_ + d];
  }
  entsum[d] = (s0 + s1) + (s2 + s3);
}

__device__ __forceinline__ void gemm64_body(int bx, int by, const float* __restrict__ X,
                                            const int* __restrict__ gatherIdx,
                                            const float* __restrict__ emb,
                                            const float* __restrict__ W,
                                            int K, int N, int KB, float* __restrict__ part) {
  const int l  = threadIdx.x & 63;
  const int rg = __builtin_amdgcn_readfirstlane((int)(threadIdx.x >> 6));
  const int c  = bx * 64 + l;
  const int k0 = by * KB;
  const int m0 = rg * 16;

  const float* Xp = gatherIdx ? emb : X;
  int rb[16];
#pragma unroll
  for (int r = 0; r < 16; ++r) {
    int m = m0 + r;
    rb[r] = gatherIdx ? gatherIdx[m] * K : m * K;
  }

  float acc[16];
#pragma unroll
  for (int r = 0; r < 16; ++r) acc[r] = 0.f;

  for (int k = k0; k < k0 + KB; k += 8) {
    float wv[8];
#pragma unroll
    for (int j = 0; j < 8; ++j) wv[j] = W[(size_t)(k + j) * N + c];
#pragma unroll
    for (int r = 0; r < 16; ++r) {
      float4 x0 = *(const float4*)&Xp[rb[r] + k];
      float4 x1 = *(const float4*)&Xp[rb[r] + k + 4];
      acc[r] = fmaf(x0.x, wv[0], acc[r]);
      acc[r] = fmaf(x0.y, wv[1], acc[r]);
      acc[r] = fmaf(x0.z, wv[2], acc[r]);
      acc[r] = fmaf(x0.w, wv[3], acc[r]);
      acc[r] = fmaf(x1.x, wv[4], acc[r]);
      acc[r] = fmaf(x1.y, wv[5], acc[r]);
      acc[r] = fmaf(x1.z, wv[6], acc[r]);
      acc[r] = fmaf(x1.w, wv[7], acc[r]);
    }
  }
  size_t base = (size_t)by * ((size_t)64 * N);
#pragma unroll
  for (int r = 0; r < 16; ++r) part[base + (size_t)(m0 + r) * N + c] = acc[r];
}

__device__ __forceinline__ void reduce_ep_body(int bid, const float* __restrict__ part,
                                               int nsplit, int MN, int N,
                                               const float* __restrict__ vecB,
                                               const float* __restrict__ addend,
                                               int mode, float* __restrict__ dst,
                                               unsigned short* __restrict__ dhi,
                                               unsigned short* __restrict__ dlo) {
  int idx = bid * 256 + threadIdx.x;
  if (idx >= MN) return;
  float s = 0.f;
  for (int i = 0; i < nsplit; ++i) s += part[(size_t)i * MN + idx];
  int c = idx & (N - 1);
  if (mode == 1)      { s += vecB[c]; s = s > 0.f ? s : 0.f; dst[idx] = s; }
  else if (mode == 2) { s += vecB[c]; dst[idx] = s; }
  else if (mode == 3) { s *= vecB[c]; dst[idx] = s; }
  else {
    s += addend[idx];
    unsigned hi = rne1(s);
    float hif = __uint_as_float(hi << 16);
    dhi[idx] = (unsigned short)hi;
    dlo[idx] = (unsigned short)rne1(s - hif);
  }
}

// ---------------- fused phase kernels (round-8 proven) ----------------
__global__ void k_p1(const float* __restrict__ eh, const void* __restrict__ mask,
                     float* __restrict__ entpart, const int* __restrict__ ques,
                     const float* __restrict__ emb, const float* __restrict__ W1,
                     float* __restrict__ gpart) {
  int bid = blockIdx.x;
  if (bid < 512) ent_partial_body(bid, eh, mask, entpart);
  else {
    int b2 = bid - 512;
    gemm64_body(b2 & 31, b2 >> 5, nullptr, ques, emb, W1, 1024, 2048, 64, gpart);
  }
}

__global__ void k_p2(const float* __restrict__ entpart, float* __restrict__ entsum,
                     const float* __restrict__ gpart, const float* __restrict__ b1,
                     float* __restrict__ hbuf) {
  int bid = blockIdx.x;
  if (bid < 4) ent_reduce_body(bid, entpart, entsum);
  else reduce_ep_body(bid - 4, gpart, 16, 64 * 2048, 2048, b1, nullptr, 1, hbuf, nullptr, nullptr);
}

__global__ void k_gemm64(const float* __restrict__ X, const float* __restrict__ W,
                         int K, int N, int KB, float* __restrict__ part) {
  gemm64_body(blockIdx.x, blockIdx.y, X, nullptr, nullptr, W, K, N, KB, part);
}

__global__ void k_reduce_ep(const float* __restrict__ part, int nsplit, int MN, int N,
                            const float* __restrict__ vecB, const float* __restrict__ addend,
                            int mode, float* __restrict__ dst,
                            unsigned short* __restrict__ dhi, unsigned short* __restrict__ dlo) {
  reduce_ep_body(blockIdx.x, part, nsplit, MN, N, vecB, addend, mode, dst, dhi, dlo);
}

// ---------------- big GEMM: split-K partials, 512-col tiles, split-bf16 MFMA -------------
// Round-11 structure scaled to 2 KB DRAM chunks: block tile = 512 cols x 512 K-rows
// (grid 99 x 2 K-halves = 198 blocks). LDS: 2 bufs of 32 x 512 f32, row stride 514
// (8*514 mod 32 = 16 -> g-groups at bank offsets {0,16}: 2-way, free). 131.6 KB LDS ->
// 1 block/CU (static LDS > 64 KB verified working in round 11). 512 thr = 8 waves; wave
// owns 64 cols = 4 N-tiles x 4 M-tiles (acc 64 VGPR; launch_bounds(512,1) -> no spill).
// Same proven stage/drain discipline: z-frags first, stage next 64 KB tile via
// global_load_lds size=4 (wave w stages rows w*4..w*4+3, 8 chunks/row), compute,
// __syncthreads. Writes per-split partials (no bias); k_redbias reduces.
__global__ __launch_bounds__(512, 1) void k_gemm_big(const unsigned short* __restrict__ zhi,
                                                     const unsigned short* __restrict__ zlo,
                                                     const float* __restrict__ Ws,
                                                     float* __restrict__ part2) {
  __shared__ float lds[2][32 * 514];   // 131,584 B
  const int t   = threadIdx.x;
  const int l   = t & 63;
  const int w   = t >> 6;              // 0..7
  const int col = l & 15;
  const int g   = l >> 4;              // k-chunk g*8..g*8+7
  const int c0  = blockIdx.x * 512;
  const int kbase = blockIdx.y * 512;

  int scol[8];
#pragma unroll
  for (int j = 0; j < 8; ++j) {
    int s = c0 + j * 64 + l;
    scol[j] = s < V_ ? s : V_ - 1;
  }

  unsigned aoff[4];
#pragma unroll
  for (int m = 0; m < 4; ++m) aoff[m] = (unsigned)((m * 16 + col) * D_ + g * 8);

  f32x4 acc[4][4];  // [n][m]
#pragma unroll
  for (int n = 0; n < 4; ++n)
#pragma unroll
    for (int m = 0; m < 4; ++m) acc[n][m] = (f32x4){0.f, 0.f, 0.f, 0.f};

  // prologue: stage tile 0. wave w stages rows w*4..w*4+3, 8 chunks (256 B DMA) each.
#pragma unroll
  for (int i = 0; i < 4; ++i) {
    const int r = w * 4 + i;
#pragma unroll
    for (int j = 0; j < 8; ++j) {
      __builtin_amdgcn_global_load_lds(
          (const __attribute__((address_space(1))) void*)(Ws + (size_t)(kbase + r) * V_ + scol[j]),
          (__attribute__((address_space(3))) void*)&lds[0][r * 514 + j * 64],
          4, 0, 0);
    }
  }
  __syncthreads();

  for (int it = 0; it < 16; ++it) {
    const int buf = it & 1;
    const int k0  = kbase + it * 32;

    // A-fragments first: their counted vmcnt wait leaves staging DMA in flight.
    bf16x8 ah[4], al[4];
#pragma unroll
    for (int m = 0; m < 4; ++m) {
      ah[m] = *(const bf16x8*)(zhi + aoff[m] + k0);
      al[m] = *(const bf16x8*)(zlo + aoff[m] + k0);
    }

    if (it + 1 < 16) {
      const float* wb = Ws + (size_t)(k0 + 32) * V_;
#pragma unroll
      for (int i = 0; i < 4; ++i) {
        const int r = w * 4 + i;
#pragma unroll
        for (int j = 0; j < 8; ++j) {
          __builtin_amdgcn_global_load_lds(
              (const __attribute__((address_space(1))) void*)(wb + (size_t)r * V_ + scol[j]),
              (__attribute__((address_space(3))) void*)&lds[buf ^ 1][r * 514 + j * 64],
              4, 0, 0);
        }
      }
    }

#pragma unroll
    for (int n = 0; n < 4; ++n) {
      float f[8];
#pragma unroll
      for (int j = 0; j < 8; ++j)
        f[j] = lds[buf][(g * 8 + j) * 514 + w * 64 + n * 16 + col];

      union { bf16x8 v; unsigned u[4]; } bh, bl;
#pragma unroll
      for (int j = 0; j < 4; ++j) {
        unsigned h0 = rne1(f[2 * j]);
        unsigned h1 = rne1(f[2 * j + 1]);
        float h0f = __uint_as_float(h0 << 16);
        float h1f = __uint_as_float(h1 << 16);
        bh.u[j] = h0 | (h1 << 16);
        bl.u[j] = rne1(f[2 * j] - h0f) | (rne1(f[2 * j + 1] - h1f) << 16);
      }
#pragma unroll
      for (int m = 0; m < 4; ++m) acc[n][m] = __builtin_amdgcn_mfma_f32_16x16x32_bf16(ah[m], bh.v, acc[n][m], 0, 0, 0);
#pragma unroll
      for (int m = 0; m < 4; ++m) acc[n][m] = __builtin_amdgcn_mfma_f32_16x16x32_bf16(ah[m], bl.v, acc[n][m], 0, 0, 0);
#pragma unroll
      for (int m = 0; m < 4; ++m) acc[n][m] = __builtin_amdgcn_mfma_f32_16x16x32_bf16(al[m], bh.v, acc[n][m], 0, 0, 0);
    }

    __syncthreads();
  }

  float* pout = part2 + (size_t)blockIdx.y * ((size_t)64 * V_);
#pragma unroll
  for (int n = 0; n < 4; ++n) {
    const int c = c0 + w * 64 + n * 16 + col;
    if (c < V_) {
#pragma unroll
      for (int m = 0; m < 4; ++m)
#pragma unroll
        for (int i = 0; i < 4; ++i)
          pout[(size_t)(m * 16 + g * 4 + i) * V_ + c] = acc[n][m][i];
    }
  }
}

// reduce 2 split-K partials + bias -> logits. Row-chunked like softmax (V odd, no mask).
#define SM_CHUNK 12565  // 4 * 12565 >= V_

__global__ void k_redbias(const float* __restrict__ part2, const float* __restrict__ bs,
                          float* __restrict__ logits) {
  const int r = blockIdx.x >> 2, q = blockIdx.x & 3;
  const int beg = q * SM_CHUNK;
  const int end = (beg + SM_CHUNK < V_) ? beg + SM_CHUNK : V_;
  const float* p0 = part2 + (size_t)r * V_;
  const float* p1 = part2 + (size_t)64 * V_ + (size_t)r * V_;
  float* orow = logits + (size_t)r * V_;
  for (int i = beg + threadIdx.x; i < end; i += 256) orow[i] = p0[i] + p1[i] + bs[i];
}

// ---------------- softmax over rows of logits [64, V], two-pass 256-block ----------------

__global__ void k_softmax1(const float* __restrict__ logits, float2* __restrict__ stats) {
  __shared__ float smx[4], ssum[4];
  const int r = blockIdx.x >> 2, q = blockIdx.x & 3;
  const int beg = q * SM_CHUNK;
  const int end = (beg + SM_CHUNK < V_) ? beg + SM_CHUNK : V_;
  const float* row = logits + (size_t)r * V_;

  float mx = -3.4e38f;
  for (int i = beg + threadIdx.x; i < end; i += 256) mx = fmaxf(mx, row[i]);
  mx = waveMax(mx);
  if ((threadIdx.x & 63) == 0) smx[threadIdx.x >> 6] = mx;
  __syncthreads();
  mx = fmaxf(fmaxf(smx[0], smx[1]), fmaxf(smx[2], smx[3]));

  float s = 0.f;
  for (int i = beg + threadIdx.x; i < end; i += 256) s += __expf(row[i] - mx);
  s = waveSum(s);
  if ((threadIdx.x & 63) == 0) ssum[threadIdx.x >> 6] = s;
  __syncthreads();
  s = (ssum[0] + ssum[1]) + (ssum[2] + ssum[3]);

  if (threadIdx.x == 0) stats[blockIdx.x] = make_float2(mx, s);
}

__global__ void k_softmax2(const float* __restrict__ logits, const float2* __restrict__ stats,
                           float* __restrict__ out) {
  const int r = blockIdx.x >> 2, q = blockIdx.x & 3;
  float2 s0 = stats[r * 4 + 0], s1 = stats[r * 4 + 1];
  float2 s2 = stats[r * 4 + 2], s3 = stats[r * 4 + 3];
  float M = fmaxf(fmaxf(s0.x, s1.x), fmaxf(s2.x, s3.x));
  float S = s0.y * __expf(s0.x - M) + s1.y * __expf(s1.x - M)
          + s2.y * __expf(s2.x - M) + s3.y * __expf(s3.x - M);
  float inv = 1.f / S;
  const int beg = q * SM_CHUNK;
  const int end = (beg + SM_CHUNK < V_) ? beg + SM_CHUNK : V_;
  const float* row = logits + (size_t)r * V_;
  float* orow = out + (size_t)r * V_;
  for (int i = beg + threadIdx.x; i < end; i += 256) orow[i] = __expf(row[i] - M) * inv;
}

// ---------------- launch ----------------
extern "C" void kernel_launch(void* const* d_in, const int* in_sizes, int n_in,
                              void* d_out, int out_size, void* d_ws, size_t ws_size,
                              hipStream_t stream) {
  const float* eh   = (const float*)d_in[0];
  const int*   ques = (const int*)d_in[1];
  const void*  mask = d_in[2];
  const float* emb  = (const float*)d_in[3];
  const float* W1   = (const float*)d_in[4];
  const float* b1   = (const float*)d_in[5];
  const float* W2   = (const float*)d_in[6];
  const float* b2   = (const float*)d_in[7];
  const float* A    = (const float*)d_in[8];
  const float* H    = (const float*)d_in[9];
  const float* Ws   = (const float*)d_in[10];
  const float* bs   = (const float*)d_in[11];
  float* out = (float*)d_out;
  char* ws = (char*)d_ws;

  // ws layout (bytes). gpart aliases logits (temporally disjoint). part2 in fresh region
  // (ws_size ~800 MB per harness fill evidence).
  float*          logits  = (float*)(ws + 0);           // 12,865,792
  float*          gpart   = (float*)(ws + 0);           // max 8,388,608 (aliased)
  float*          entpart = (float*)(ws + 12866048);    // 2,097,152
  float*          entsum  = (float*)(ws + 14963200);    // 4,096
  float*          hbuf    = (float*)(ws + 14967296);    // 524,288
  float*          qbuf    = (float*)(ws + 15491584);    // 262,144
  float*          ubuf    = (float*)(ws + 15753728);    // 262,144
  unsigned short* zhi16   = (unsigned short*)(ws + 16015872);  // 131,072
  unsigned short* zlo16   = (unsigned short*)(ws + 16146944);  // 131,072
  float2*         stats   = (float2*)(ws + 16278016);   // 2,048
  float*          part2   = (float*)(ws + 20971520);    // 2*64*V*4 = 25,731,584

  // P1: ent_partial (512 blocks) || h-gemm partials (512 blocks)
  k_p1<<<1024, 256, 0, stream>>>(eh, mask, entpart, ques, emb, W1, gpart);
  // P2: ent_reduce (4) || h = relu(.+b1) (512)
  k_p2<<<516, 256, 0, stream>>>(entpart, entsum, gpart, b1, hbuf);

  // P3/P4: q = h @ W2 + b2                 [64,1024], K=2048, split 32
  k_gemm64<<<dim3(16, 32), 256, 0, stream>>>(hbuf, W2, 2048, 1024, 64, gpart);
  k_reduce_ep<<<256, 256, 0, stream>>>(gpart, 32, 64 * 1024, 1024, b2, nullptr, 2, qbuf, nullptr, nullptr);

  // P5/P6: u = (q @ A) * ent_sum           [64,1024], split 16
  k_gemm64<<<dim3(16, 16), 256, 0, stream>>>(qbuf, A, 1024, 1024, 64, gpart);
  k_reduce_ep<<<256, 256, 0, stream>>>(gpart, 16, 64 * 1024, 1024, entsum, nullptr, 3, ubuf, nullptr, nullptr);

  // P7/P8: z = q + u @ H (-> bf16 hi/lo)   [64,1024], split 16
  k_gemm64<<<dim3(16, 16), 256, 0, stream>>>(ubuf, H, 1024, 1024, 64, gpart);
  k_reduce_ep<<<256, 256, 0, stream>>>(gpart, 16, 64 * 1024, 1024, nullptr, qbuf, 4, nullptr, zhi16, zlo16);

  // P9: split-K partials = z @ Ws          [64,V]x2, 512-col tiles, LDS-staged Ws
  k_gemm_big<<<dim3(99, 2), 512, 0, stream>>>(zhi16, zlo16, Ws, part2);
  // P9b: logits = part2[0] + part2[1] + bs
  k_redbias<<<256, 256, 0, stream>>>(part2, bs, logits);

  // P10/P11: softmax two-pass
  k_softmax1<<<256, 256, 0, stream>>>(logits, stats);
  k_softmax2<<<256, 256, 0, stream>>>(logits, stats, out);

  (void)in_sizes; (void)n_in; (void)out_size; (void)ws_size;
}

// Round 13
// 268.700 us; speedup vs baseline: 1.2528x; 1.0195x over previous
//
#include <hip/hip_runtime.h>
#include <stdint.h>

#define V_ 50257
#define D_ 1024
#define F_ 2048
#define B_ 64
#define E_ 512
#define ROWS_ (B_*E_)

typedef __attribute__((ext_vector_type(8))) short bf16x8;
typedef __attribute__((ext_vector_type(4))) float f32x4;
typedef __attribute__((ext_vector_type(4), aligned(4))) float f32x4a;  // 4B-aligned global loads

__device__ __forceinline__ unsigned rne1(float a) {
  unsigned u = __float_as_uint(a);
  return (u + 0x7FFFu + ((u >> 16) & 1u)) >> 16;
}

__device__ __forceinline__ float waveMax(float v) {
#pragma unroll
  for (int o = 32; o > 0; o >>= 1) v = fmaxf(v, __shfl_xor(v, o, 64));
  return v;
}
__device__ __forceinline__ float waveSum(float v) {
#pragma unroll
  for (int o = 32; o > 0; o >>= 1) v += __shfl_xor(v, o, 64);
  return v;
}

// ---------------- device bodies (round-8 proven versions) ----------------

__device__ __forceinline__ void ent_partial_body(int bid, const float* __restrict__ eh,
                                                 const void* __restrict__ mask,
                                                 float* __restrict__ part) {
  __shared__ int s_mode;
  const int tid = threadIdx.x;
  const uint32_t* mu = (const uint32_t*)mask;
  int f = 0;
  for (int i = tid; i < (ROWS_ / 4); i += 256) {
    uint32_t u = mu[i];
    if (u == 0x3F800000u) f |= 2;
    else if (u & 0xFFFFFF00u) f |= 1;
  }
  if (tid == 0) s_mode = 0;
  __syncthreads();
  if (f) atomicOr(&s_mode, f);
  __syncthreads();
  const int sm = s_mode;
  const int mode = (sm & 1) ? 1 : ((sm & 2) ? 2 : 0);

  float4 acc = make_float4(0.f, 0.f, 0.f, 0.f);
  const float4* eh4 = (const float4*)eh;
  for (int row = bid; row < ROWS_; row += 512) {
    bool on;
    if (mode == 1)      on = ((const unsigned char*)mask)[row] != 0;
    else if (mode == 2) on = ((const float*)mask)[row] != 0.f;
    else                on = ((const int*)mask)[row] != 0;
    if (on) {
      float4 v = eh4[(size_t)row * (D_ / 4) + tid];
      acc.x += v.x; acc.y += v.y; acc.z += v.z; acc.w += v.w;
    }
  }
  ((float4*)part)[(size_t)bid * (D_ / 4) + tid] = acc;
}

__device__ __forceinline__ void ent_reduce_body(int bid, const float* __restrict__ part,
                                                float* __restrict__ entsum) {
  int d = bid * 256 + threadIdx.x;
  float s0 = 0.f, s1 = 0.f, s2 = 0.f, s3 = 0.f;
  for (int i = 0; i < 512; i += 4) {
    s0 += part[(size_t)(i    ) * D_ + d];
    s1 += part[(size_t)(i + 1) * D_ + d];
    s2 += part[(size_t)(i + 2) * D_ + d];
    s3 += part[(size_t)(i + 3) * D_ + d];
  }
  entsum[d] = (s0 + s1) + (s2 + s3);
}

__device__ __forceinline__ void gemm64_body(int bx, int by, const float* __restrict__ X,
                                            const int* __restrict__ gatherIdx,
                                            const float* __restrict__ emb,
                                            const float* __restrict__ W,
                                            int K, int N, int KB, float* __restrict__ part) {
  const int l  = threadIdx.x & 63;
  const int rg = __builtin_amdgcn_readfirstlane((int)(threadIdx.x >> 6));
  const int c  = bx * 64 + l;
  const int k0 = by * KB;
  const int m0 = rg * 16;

  const float* Xp = gatherIdx ? emb : X;
  int rb[16];
#pragma unroll
  for (int r = 0; r < 16; ++r) {
    int m = m0 + r;
    rb[r] = gatherIdx ? gatherIdx[m] * K : m * K;
  }

  float acc[16];
#pragma unroll
  for (int r = 0; r < 16; ++r) acc[r] = 0.f;

  for (int k = k0; k < k0 + KB; k += 8) {
    float wv[8];
#pragma unroll
    for (int j = 0; j < 8; ++j) wv[j] = W[(size_t)(k + j) * N + c];
#pragma unroll
    for (int r = 0; r < 16; ++r) {
      float4 x0 = *(const float4*)&Xp[rb[r] + k];
      float4 x1 = *(const float4*)&Xp[rb[r] + k + 4];
      acc[r] = fmaf(x0.x, wv[0], acc[r]);
      acc[r] = fmaf(x0.y, wv[1], acc[r]);
      acc[r] = fmaf(x0.z, wv[2], acc[r]);
      acc[r] = fmaf(x0.w, wv[3], acc[r]);
      acc[r] = fmaf(x1.x, wv[4], acc[r]);
      acc[r] = fmaf(x1.y, wv[5], acc[r]);
      acc[r] = fmaf(x1.z, wv[6], acc[r]);
      acc[r] = fmaf(x1.w, wv[7], acc[r]);
    }
  }
  size_t base = (size_t)by * ((size_t)64 * N);
#pragma unroll
  for (int r = 0; r < 16; ++r) part[base + (size_t)(m0 + r) * N + c] = acc[r];
}

__device__ __forceinline__ void reduce_ep_body(int bid, const float* __restrict__ part,
                                               int nsplit, int MN, int N,
                                               const float* __restrict__ vecB,
                                               const float* __restrict__ addend,
                                               int mode, float* __restrict__ dst,
                                               unsigned short* __restrict__ dhi,
                                               unsigned short* __restrict__ dlo) {
  int idx = bid * 256 + threadIdx.x;
  if (idx >= MN) return;
  float s = 0.f;
  for (int i = 0; i < nsplit; ++i) s += part[(size_t)i * MN + idx];
  int c = idx & (N - 1);
  if (mode == 1)      { s += vecB[c]; s = s > 0.f ? s : 0.f; dst[idx] = s; }
  else if (mode == 2) { s += vecB[c]; dst[idx] = s; }
  else if (mode == 3) { s *= vecB[c]; dst[idx] = s; }
  else {
    s += addend[idx];
    unsigned hi = rne1(s);
    float hif = __uint_as_float(hi << 16);
    dhi[idx] = (unsigned short)hi;
    dlo[idx] = (unsigned short)rne1(s - hif);
  }
}

// ---------------- fused phase kernels (round-8 proven) ----------------
__global__ void k_p1(const float* __restrict__ eh, const void* __restrict__ mask,
                     float* __restrict__ entpart, const int* __restrict__ ques,
                     const float* __restrict__ emb, const float* __restrict__ W1,
                     float* __restrict__ gpart) {
  int bid = blockIdx.x;
  if (bid < 512) ent_partial_body(bid, eh, mask, entpart);
  else {
    int b2 = bid - 512;
    gemm64_body(b2 & 31, b2 >> 5, nullptr, ques, emb, W1, 1024, 2048, 64, gpart);
  }
}

__global__ void k_p2(const float* __restrict__ entpart, float* __restrict__ entsum,
                     const float* __restrict__ gpart, const float* __restrict__ b1,
                     float* __restrict__ hbuf) {
  int bid = blockIdx.x;
  if (bid < 4) ent_reduce_body(bid, entpart, entsum);
  else reduce_ep_body(bid - 4, gpart, 16, 64 * 2048, 2048, b1, nullptr, 1, hbuf, nullptr, nullptr);
}

__global__ void k_gemm64(const float* __restrict__ X, const float* __restrict__ W,
                         int K, int N, int KB, float* __restrict__ part) {
  gemm64_body(blockIdx.x, blockIdx.y, X, nullptr, nullptr, W, K, N, KB, part);
}

__global__ void k_reduce_ep(const float* __restrict__ part, int nsplit, int MN, int N,
                            const float* __restrict__ vecB, const float* __restrict__ addend,
                            int mode, float* __restrict__ dst,
                            unsigned short* __restrict__ dhi, unsigned short* __restrict__ dlo) {
  reduce_ep_body(blockIdx.x, part, nsplit, MN, N, vecB, addend, mode, dst, dhi, dlo);
}

// ---------------- big GEMM: split-K partials, 512-col tiles, split-bf16 MFMA -------------
// Round-13 change (one lever): staging DMA (size-4 global_load_lds = 256 B/instr) replaced
// by register-staged float4 loads (16 B/lane -> 1 KB contiguous per wave-instruction) +
// ds_write_b128. Theory: rounds 3-12's ~1-2 TB/s Ws plateau is per-instruction request
// width; every fast stream on this machine (fill 7 TB/s, entity read, spills) is dwordx4.
// Order per iter: z(t) loads, Ws(t+1) loads, sched_barrier (pins loads against r5-7
// sink-to-use), compute(t) (waits z via counted vmcnt, Ws stays in flight), sched_barrier,
// ds_write(t+1) (its vmcnt dependency has had the whole compute to land), __syncthreads.
// LDS stride 516: rows 16B-aligned -> conflict-free b128 writes; 4-way read conflict
// (~100cy/iter/wave) accepted. Tail block shifts c0 to V-512 (overlap computed twice,
// identical values -> benign double-write; per-col data stays correctly aligned).
__global__ __launch_bounds__(512, 1) void k_gemm_big(const unsigned short* __restrict__ zhi,
                                                     const unsigned short* __restrict__ zlo,
                                                     const float* __restrict__ Ws,
                                                     float* __restrict__ part2) {
  __shared__ float lds[2][32 * 516];   // 132,096 B
  const int t   = threadIdx.x;
  const int l   = t & 63;
  const int w   = t >> 6;              // 0..7
  const int col = l & 15;
  const int g   = l >> 4;              // k-chunk g*8..g*8+7
  const int c0  = (blockIdx.x < 98) ? blockIdx.x * 512 : (V_ - 512);
  const int kbase = blockIdx.y * 512;

  // staging map: thread t covers rows (t>>7) + 4*r8 (r8=0..7), cols ccf..ccf+3 of the tile
  const int rr0 = t >> 7;              // 0..3
  const int ccf = (t & 127) * 4;       // 0..508

  unsigned aoff[4];
#pragma unroll
  for (int m = 0; m < 4; ++m) aoff[m] = (unsigned)((m * 16 + col) * D_ + g * 8);

  f32x4 acc[4][4];  // [n][m]
#pragma unroll
  for (int n = 0; n < 4; ++n)
#pragma unroll
    for (int m = 0; m < 4; ++m) acc[n][m] = (f32x4){0.f, 0.f, 0.f, 0.f};

  // prologue: stage tile 0 through registers
  {
    f32x4a gg[8];
#pragma unroll
    for (int r8 = 0; r8 < 8; ++r8) {
      const int r = r8 * 4 + rr0;
      gg[r8] = *(const f32x4a*)(Ws + (size_t)(kbase + r) * V_ + c0 + ccf);
    }
#pragma unroll
    for (int r8 = 0; r8 < 8; ++r8) {
      const int r = r8 * 4 + rr0;
      *(f32x4*)&lds[0][r * 516 + ccf] = (f32x4)gg[r8];
    }
  }
  __syncthreads();

  for (int tt = 0; tt < 16; ++tt) {
    const int buf = tt & 1;
    const int k0  = kbase + tt * 32;

    // z-fragments first (oldest): compute's wait for them leaves Ws loads in flight.
    bf16x8 ah[4], al[4];
#pragma unroll
    for (int m = 0; m < 4; ++m) {
      ah[m] = *(const bf16x8*)(zhi + aoff[m] + k0);
      al[m] = *(const bf16x8*)(zlo + aoff[m] + k0);
    }

    // next Ws tile -> registers (1 KB contiguous per wave-instruction)
    f32x4a gg[8];
    if (tt + 1 < 16) {
      const float* wb = Ws + (size_t)(k0 + 32) * V_ + c0 + ccf;
#pragma unroll
      for (int r8 = 0; r8 < 8; ++r8)
        gg[r8] = *(const f32x4a*)(wb + (size_t)(r8 * 4 + rr0) * V_);
    }
    __builtin_amdgcn_sched_barrier(0);

    // compute tile tt from lds[buf]
#pragma unroll
    for (int n = 0; n < 4; ++n) {
      float f[8];
#pragma unroll
      for (int j = 0; j < 8; ++j)
        f[j] = lds[buf][(g * 8 + j) * 516 + w * 64 + n * 16 + col];

      union { bf16x8 v; unsigned u[4]; } bh, bl;
#pragma unroll
      for (int j = 0; j < 4; ++j) {
        unsigned h0 = rne1(f[2 * j]);
        unsigned h1 = rne1(f[2 * j + 1]);
        float h0f = __uint_as_float(h0 << 16);
        float h1f = __uint_as_float(h1 << 16);
        bh.u[j] = h0 | (h1 << 16);
        bl.u[j] = rne1(f[2 * j] - h0f) | (rne1(f[2 * j + 1] - h1f) << 16);
      }
#pragma unroll
      for (int m = 0; m < 4; ++m) acc[n][m] = __builtin_amdgcn_mfma_f32_16x16x32_bf16(ah[m], bh.v, acc[n][m], 0, 0, 0);
#pragma unroll
      for (int m = 0; m < 4; ++m) acc[n][m] = __builtin_amdgcn_mfma_f32_16x16x32_bf16(ah[m], bl.v, acc[n][m], 0, 0, 0);
#pragma unroll
      for (int m = 0; m < 4; ++m) acc[n][m] = __builtin_amdgcn_mfma_f32_16x16x32_bf16(al[m], bh.v, acc[n][m], 0, 0, 0);
    }
    __builtin_amdgcn_sched_barrier(0);

    // write next tile to the other buffer (b128, conflict-free, 16B-aligned rows)
    if (tt + 1 < 16) {
#pragma unroll
      for (int r8 = 0; r8 < 8; ++r8) {
        const int r = r8 * 4 + rr0;
        *(f32x4*)&lds[buf ^ 1][r * 516 + ccf] = (f32x4)gg[r8];
      }
    }
    __syncthreads();
  }

  float* pout = part2 + (size_t)blockIdx.y * ((size_t)64 * V_);
#pragma unroll
  for (int n = 0; n < 4; ++n) {
    const int c = c0 + w * 64 + n * 16 + col;
    if (c < V_) {
#pragma unroll
      for (int m = 0; m < 4; ++m)
#pragma unroll
        for (int i = 0; i < 4; ++i)
          pout[(size_t)(m * 16 + g * 4 + i) * V_ + c] = acc[n][m][i];
    }
  }
}

// reduce 2 split-K partials + bias -> logits. Row-chunked like softmax (V odd, no mask).
#define SM_CHUNK 12565  // 4 * 12565 >= V_

__global__ void k_redbias(const float* __restrict__ part2, const float* __restrict__ bs,
                          float* __restrict__ logits) {
  const int r = blockIdx.x >> 2, q = blockIdx.x & 3;
  const int beg = q * SM_CHUNK;
  const int end = (beg + SM_CHUNK < V_) ? beg + SM_CHUNK : V_;
  const float* p0 = part2 + (size_t)r * V_;
  const float* p1 = part2 + (size_t)64 * V_ + (size_t)r * V_;
  float* orow = logits + (size_t)r * V_;
  for (int i = beg + threadIdx.x; i < end; i += 256) orow[i] = p0[i] + p1[i] + bs[i];
}

// ---------------- softmax over rows of logits [64, V], two-pass 256-block ----------------

__global__ void k_softmax1(const float* __restrict__ logits, float2* __restrict__ stats) {
  __shared__ float smx[4], ssum[4];
  const int r = blockIdx.x >> 2, q = blockIdx.x & 3;
  const int beg = q * SM_CHUNK;
  const int end = (beg + SM_CHUNK < V_) ? beg + SM_CHUNK : V_;
  const float* row = logits + (size_t)r * V_;

  float mx = -3.4e38f;
  for (int i = beg + threadIdx.x; i < end; i += 256) mx = fmaxf(mx, row[i]);
  mx = waveMax(mx);
  if ((threadIdx.x & 63) == 0) smx[threadIdx.x >> 6] = mx;
  __syncthreads();
  mx = fmaxf(fmaxf(smx[0], smx[1]), fmaxf(smx[2], smx[3]));

  float s = 0.f;
  for (int i = beg + threadIdx.x; i < end; i += 256) s += __expf(row[i] - mx);
  s = waveSum(s);
  if ((threadIdx.x & 63) == 0) ssum[threadIdx.x >> 6] = s;
  __syncthreads();
  s = (ssum[0] + ssum[1]) + (ssum[2] + ssum[3]);

  if (threadIdx.x == 0) stats[blockIdx.x] = make_float2(mx, s);
}

__global__ void k_softmax2(const float* __restrict__ logits, const float2* __restrict__ stats,
                           float* __restrict__ out) {
  const int r = blockIdx.x >> 2, q = blockIdx.x & 3;
  float2 s0 = stats[r * 4 + 0], s1 = stats[r * 4 + 1];
  float2 s2 = stats[r * 4 + 2], s3 = stats[r * 4 + 3];
  float M = fmaxf(fmaxf(s0.x, s1.x), fmaxf(s2.x, s3.x));
  float S = s0.y * __expf(s0.x - M) + s1.y * __expf(s1.x - M)
          + s2.y * __expf(s2.x - M) + s3.y * __expf(s3.x - M);
  float inv = 1.f / S;
  const int beg = q * SM_CHUNK;
  const int end = (beg + SM_CHUNK < V_) ? beg + SM_CHUNK : V_;
  const float* row = logits + (size_t)r * V_;
  float* orow = out + (size_t)r * V_;
  for (int i = beg + threadIdx.x; i < end; i += 256) orow[i] = __expf(row[i] - M) * inv;
}

// ---------------- launch ----------------
extern "C" void kernel_launch(void* const* d_in, const int* in_sizes, int n_in,
                              void* d_out, int out_size, void* d_ws, size_t ws_size,
                              hipStream_t stream) {
  const float* eh   = (const float*)d_in[0];
  const int*   ques = (const int*)d_in[1];
  const void*  mask = d_in[2];
  const float* emb  = (const float*)d_in[3];
  const float* W1   = (const float*)d_in[4];
  const float* b1   = (const float*)d_in[5];
  const float* W2   = (const float*)d_in[6];
  const float* b2   = (const float*)d_in[7];
  const float* A    = (const float*)d_in[8];
  const float* H    = (const float*)d_in[9];
  const float* Ws   = (const float*)d_in[10];
  const float* bs   = (const float*)d_in[11];
  float* out = (float*)d_out;
  char* ws = (char*)d_ws;

  // ws layout (bytes). gpart aliases logits (temporally disjoint). part2 in fresh region.
  float*          logits  = (float*)(ws + 0);           // 12,865,792
  float*          gpart   = (float*)(ws + 0);           // max 8,388,608 (aliased)
  float*          entpart = (float*)(ws + 12866048);    // 2,097,152
  float*          entsum  = (float*)(ws + 14963200);    // 4,096
  float*          hbuf    = (float*)(ws + 14967296);    // 524,288
  float*          qbuf    = (float*)(ws + 15491584);    // 262,144
  float*          ubuf    = (float*)(ws + 15753728);    // 262,144
  unsigned short* zhi16   = (unsigned short*)(ws + 16015872);  // 131,072
  unsigned short* zlo16   = (unsigned short*)(ws + 16146944);  // 131,072
  float2*         stats   = (float2*)(ws + 16278016);   // 2,048
  float*          part2   = (float*)(ws + 20971520);    // 2*64*V*4 = 25,731,584

  // P1: ent_partial (512 blocks) || h-gemm partials (512 blocks)
  k_p1<<<1024, 256, 0, stream>>>(eh, mask, entpart, ques, emb, W1, gpart);
  // P2: ent_reduce (4) || h = relu(.+b1) (512)
  k_p2<<<516, 256, 0, stream>>>(entpart, entsum, gpart, b1, hbuf);

  // P3/P4: q = h @ W2 + b2                 [64,1024], K=2048, split 32
  k_gemm64<<<dim3(16, 32), 256, 0, stream>>>(hbuf, W2, 2048, 1024, 64, gpart);
  k_reduce_ep<<<256, 256, 0, stream>>>(gpart, 32, 64 * 1024, 1024, b2, nullptr, 2, qbuf, nullptr, nullptr);

  // P5/P6: u = (q @ A) * ent_sum           [64,1024], split 16
  k_gemm64<<<dim3(16, 16), 256, 0, stream>>>(qbuf, A, 1024, 1024, 64, gpart);
  k_reduce_ep<<<256, 256, 0, stream>>>(gpart, 16, 64 * 1024, 1024, entsum, nullptr, 3, ubuf, nullptr, nullptr);

  // P7/P8: z = q + u @ H (-> bf16 hi/lo)   [64,1024], split 16
  k_gemm64<<<dim3(16, 16), 256, 0, stream>>>(ubuf, H, 1024, 1024, 64, gpart);
  k_reduce_ep<<<256, 256, 0, stream>>>(gpart, 16, 64 * 1024, 1024, nullptr, qbuf, 4, nullptr, zhi16, zlo16);

  // P9: split-K partials = z @ Ws          [64,V]x2, 512-col tiles, reg-staged f32x4
  k_gemm_big<<<dim3(99, 2), 512, 0, stream>>>(zhi16, zlo16, Ws, part2);
  // P9b: logits = part2[0] + part2[1] + bs
  k_redbias<<<256, 256, 0, stream>>>(part2, bs, logits);

  // P10/P11: softmax two-pass
  k_softmax1<<<256, 256, 0, stream>>>(logits, stats);
  k_softmax2<<<256, 256, 0, stream>>>(logits, stats, out);

  (void)in_sizes; (void)n_in; (void)out_size; (void)ws_size;
}

// Round 14
// 252.498 us; speedup vs baseline: 1.3332x; 1.0642x over previous
//
#include <hip/hip_runtime.h>
#include <stdint.h>

#define V_ 50257
#define D_ 1024
#define F_ 2048
#define B_ 64
#define E_ 512
#define ROWS_ (B_*E_)

typedef __attribute__((ext_vector_type(8))) short bf16x8;
typedef __attribute__((ext_vector_type(4))) float f32x4;
typedef __attribute__((ext_vector_type(4), aligned(4))) float f32x4a;  // 4B-aligned global loads

__device__ __forceinline__ unsigned rne1(float a) {
  unsigned u = __float_as_uint(a);
  return (u + 0x7FFFu + ((u >> 16) & 1u)) >> 16;
}

__device__ __forceinline__ float waveMax(float v) {
#pragma unroll
  for (int o = 32; o > 0; o >>= 1) v = fmaxf(v, __shfl_xor(v, o, 64));
  return v;
}
__device__ __forceinline__ float waveSum(float v) {
#pragma unroll
  for (int o = 32; o > 0; o >>= 1) v += __shfl_xor(v, o, 64);
  return v;
}

// ---------------- device bodies ----------------

__device__ __forceinline__ void ent_partial_body(int bid, const float* __restrict__ eh,
                                                 const void* __restrict__ mask,
                                                 float* __restrict__ part) {
  __shared__ int s_mode;
  const int tid = threadIdx.x;
  const uint32_t* mu = (const uint32_t*)mask;
  int f = 0;
  for (int i = tid; i < (ROWS_ / 4); i += 256) {
    uint32_t u = mu[i];
    if (u == 0x3F800000u) f |= 2;
    else if (u & 0xFFFFFF00u) f |= 1;
  }
  if (tid == 0) s_mode = 0;
  __syncthreads();
  if (f) atomicOr(&s_mode, f);
  __syncthreads();
  const int sm = s_mode;
  const int mode = (sm & 1) ? 1 : ((sm & 2) ? 2 : 0);

  float4 acc = make_float4(0.f, 0.f, 0.f, 0.f);
  const float4* eh4 = (const float4*)eh;
  for (int row = bid; row < ROWS_; row += 512) {
    bool on;
    if (mode == 1)      on = ((const unsigned char*)mask)[row] != 0;
    else if (mode == 2) on = ((const float*)mask)[row] != 0.f;
    else                on = ((const int*)mask)[row] != 0;
    if (on) {
      float4 v = eh4[(size_t)row * (D_ / 4) + tid];
      acc.x += v.x; acc.y += v.y; acc.z += v.z; acc.w += v.w;
    }
  }
  ((float4*)part)[(size_t)bid * (D_ / 4) + tid] = acc;
}

__device__ __forceinline__ void ent_reduce_body(int bid, const float* __restrict__ part,
                                                float* __restrict__ entsum) {
  int d = bid * 256 + threadIdx.x;
  float s0 = 0.f, s1 = 0.f, s2 = 0.f, s3 = 0.f;
#pragma unroll 8
  for (int i = 0; i < 512; i += 4) {
    s0 += part[(size_t)(i    ) * D_ + d];
    s1 += part[(size_t)(i + 1) * D_ + d];
    s2 += part[(size_t)(i + 2) * D_ + d];
    s3 += part[(size_t)(i + 3) * D_ + d];
  }
  entsum[d] = (s0 + s1) + (s2 + s3);
}

__device__ __forceinline__ void gemm64_body(int bx, int by, const float* __restrict__ X,
                                            const int* __restrict__ gatherIdx,
                                            const float* __restrict__ emb,
                                            const float* __restrict__ W,
                                            int K, int N, int KB, float* __restrict__ part) {
  const int l  = threadIdx.x & 63;
  const int rg = __builtin_amdgcn_readfirstlane((int)(threadIdx.x >> 6));
  const int c  = bx * 64 + l;
  const int k0 = by * KB;
  const int m0 = rg * 16;

  const float* Xp = gatherIdx ? emb : X;
  int rb[16];
#pragma unroll
  for (int r = 0; r < 16; ++r) {
    int m = m0 + r;
    rb[r] = gatherIdx ? gatherIdx[m] * K : m * K;
  }

  float acc[16];
#pragma unroll
  for (int r = 0; r < 16; ++r) acc[r] = 0.f;

  for (int k = k0; k < k0 + KB; k += 8) {
    float wv[8];
#pragma unroll
    for (int j = 0; j < 8; ++j) wv[j] = W[(size_t)(k + j) * N + c];
#pragma unroll
    for (int r = 0; r < 16; ++r) {
      float4 x0 = *(const float4*)&Xp[rb[r] + k];
      float4 x1 = *(const float4*)&Xp[rb[r] + k + 4];
      acc[r] = fmaf(x0.x, wv[0], acc[r]);
      acc[r] = fmaf(x0.y, wv[1], acc[r]);
      acc[r] = fmaf(x0.z, wv[2], acc[r]);
      acc[r] = fmaf(x0.w, wv[3], acc[r]);
      acc[r] = fmaf(x1.x, wv[4], acc[r]);
      acc[r] = fmaf(x1.y, wv[5], acc[r]);
      acc[r] = fmaf(x1.z, wv[6], acc[r]);
      acc[r] = fmaf(x1.w, wv[7], acc[r]);
    }
  }
  size_t base = (size_t)by * ((size_t)64 * N);
#pragma unroll
  for (int r = 0; r < 16; ++r) part[base + (size_t)(m0 + r) * N + c] = acc[r];
}

// reduce split-K partials + epilogue, compile-time NSPLIT (all loads issue in parallel).
// mode 1: relu(x+vecB[c]); 2: x+vecB[c]; 3: x*vecB[c];
// mode 4: idx is the zpack DEST index; gathers src, writes bf16 hi/lo in MFMA-fragment order.
template<int NSPLIT>
__device__ __forceinline__ void reduce_body_t(int bid, const float* __restrict__ part,
                                              int MN, int N,
                                              const float* __restrict__ vecB,
                                              const float* __restrict__ addend,
                                              int mode, float* __restrict__ dst,
                                              unsigned short* __restrict__ ph,
                                              unsigned short* __restrict__ pl) {
  int idx = bid * 256 + threadIdx.x;
  if (idx >= MN) return;

  if (mode == 4) {
    // dest-indexed zpack: d -> (tg, m, l, j) -> src element (row, kk)
    const int d   = idx;
    const int j   = d & 7;
    const int l   = (d >> 3) & 63;
    const int m   = (d >> 9) & 3;
    const int tg  = d >> 11;
    const int col = l & 15;
    const int g   = l >> 4;
    const int row = m * 16 + col;
    const int kk  = tg * 32 + g * 8 + j;
    const int src = row * 1024 + kk;
    float s = 0.f;
#pragma unroll
    for (int i = 0; i < NSPLIT; ++i) s += part[(size_t)i * MN + src];
    s += addend[src];
    unsigned hi = rne1(s);
    float hif = __uint_as_float(hi << 16);
    ph[d] = (unsigned short)hi;
    pl[d] = (unsigned short)rne1(s - hif);
    return;
  }

  float s = 0.f;
#pragma unroll
  for (int i = 0; i < NSPLIT; ++i) s += part[(size_t)i * MN + idx];
  int c = idx & (N - 1);
  if (mode == 1)      { s += vecB[c]; s = s > 0.f ? s : 0.f; dst[idx] = s; }
  else if (mode == 2) { s += vecB[c]; dst[idx] = s; }
  else                { s *= vecB[c]; dst[idx] = s; }
}

// ---------------- fused phase kernels ----------------
__global__ void k_p1(const float* __restrict__ eh, const void* __restrict__ mask,
                     float* __restrict__ entpart, const int* __restrict__ ques,
                     const float* __restrict__ emb, const float* __restrict__ W1,
                     float* __restrict__ gpart) {
  int bid = blockIdx.x;
  if (bid < 512) ent_partial_body(bid, eh, mask, entpart);
  else {
    int b2 = bid - 512;
    gemm64_body(b2 & 31, b2 >> 5, nullptr, ques, emb, W1, 1024, 2048, 64, gpart);
  }
}

__global__ void k_p2(const float* __restrict__ entpart, float* __restrict__ entsum,
                     const float* __restrict__ gpart, const float* __restrict__ b1,
                     float* __restrict__ hbuf) {
  int bid = blockIdx.x;
  if (bid < 4) ent_reduce_body(bid, entpart, entsum);
  else reduce_body_t<16>(bid - 4, gpart, 64 * 2048, 2048, b1, nullptr, 1, hbuf, nullptr, nullptr);
}

__global__ void k_gemm64(const float* __restrict__ X, const float* __restrict__ W,
                         int K, int N, int KB, float* __restrict__ part) {
  gemm64_body(blockIdx.x, blockIdx.y, X, nullptr, nullptr, W, K, N, KB, part);
}

template<int NSPLIT>
__global__ void k_reduce_t(const float* __restrict__ part, int MN, int N,
                           const float* __restrict__ vecB, const float* __restrict__ addend,
                           int mode, float* __restrict__ dst,
                           unsigned short* __restrict__ ph, unsigned short* __restrict__ pl) {
  reduce_body_t<NSPLIT>(blockIdx.x, part, MN, N, vecB, addend, mode, dst, ph, pl);
}

// ---------------- big GEMM: split-K partials, 256-col tiles, split-bf16 MFMA -------------
// Round-14: (197 col-blocks x 2 K-halves) = 394 blocks -> all 256 CUs busy (was 198 at
// 1/CU; m13's 24.6 GB/s/CU makes CU coverage the floor-setter). LDS 2 x 32x260 f32 =
// 66.5 KB -> 2 blocks/CU resident. z-fragments come from zpack (pre-packed in per-lane
// MFMA order by the mode-4 epilogue): every z load is a fully coalesced 1 KB wave
// instruction (was 16 x 64 B scatter). Staging keeps the round-13 reg-staged f32x4 +
// ds_write_b128 + sched_barrier discipline. Tail col-block shifts c0 to V-256 (overlap
// cols written twice with identical values - benign, round-13 precedent).
__global__ __launch_bounds__(256, 2) void k_gemm_big(const unsigned short* __restrict__ zpkh,
                                                     const unsigned short* __restrict__ zpkl,
                                                     const float* __restrict__ Ws,
                                                     float* __restrict__ part2) {
  __shared__ float lds[2][32 * 260];   // 66,560 B
  const int t   = threadIdx.x;
  const int l   = t & 63;
  const int w   = t >> 6;              // wave 0..3
  const int col = l & 15;
  const int g   = l >> 4;              // k-chunk g*8..g*8+7
  const int c0  = (blockIdx.x < 196) ? blockIdx.x * 256 : (V_ - 256);
  const int kbase = blockIdx.y * 512;

  f32x4 acc[4][4];  // [n][m]
#pragma unroll
  for (int n = 0; n < 4; ++n)
#pragma unroll
    for (int m = 0; m < 4; ++m) acc[n][m] = (f32x4){0.f, 0.f, 0.f, 0.f};

  // prologue: stage tile 0. wave w stages rows w+4i (i=0..7); lane covers cols 4l..4l+3.
  {
    f32x4a gg[8];
#pragma unroll
    for (int i = 0; i < 8; ++i) {
      const int r = w + 4 * i;
      gg[i] = *(const f32x4a*)(Ws + (size_t)(kbase + r) * V_ + c0 + 4 * l);
    }
#pragma unroll
    for (int i = 0; i < 8; ++i) {
      const int r = w + 4 * i;
      *(f32x4*)&lds[0][r * 260 + 4 * l] = (f32x4)gg[i];
    }
  }
  __syncthreads();

  for (int tt = 0; tt < 16; ++tt) {
    const int buf = tt & 1;
    const int tg  = (kbase >> 5) + tt;

    // z-fragments first (oldest): coalesced 16B/lane from zpack; compute's wait for them
    // (counted vmcnt) leaves the Ws loads in flight.
    bf16x8 ah[4], al[4];
#pragma unroll
    for (int m = 0; m < 4; ++m) {
      const int zb = ((tg * 4 + m) * 64 + l) * 8;
      ah[m] = *(const bf16x8*)(zpkh + zb);
      al[m] = *(const bf16x8*)(zpkl + zb);
    }

    // next Ws tile -> registers (1 KB contiguous per wave-instruction)
    f32x4a gg[8];
    if (tt + 1 < 16) {
      const float* wb = Ws + (size_t)(kbase + (tt + 1) * 32) * V_ + c0 + 4 * l;
#pragma unroll
      for (int i = 0; i < 8; ++i)
        gg[i] = *(const f32x4a*)(wb + (size_t)(w + 4 * i) * V_);
    }
    __builtin_amdgcn_sched_barrier(0);

    // compute tile tt from lds[buf]
#pragma unroll
    for (int n = 0; n < 4; ++n) {
      float f[8];
#pragma unroll
      for (int j = 0; j < 8; ++j)
        f[j] = lds[buf][(g * 8 + j) * 260 + w * 64 + n * 16 + col];

      union { bf16x8 v; unsigned u[4]; } bh, bl;
#pragma unroll
      for (int j = 0; j < 4; ++j) {
        unsigned h0 = rne1(f[2 * j]);
        unsigned h1 = rne1(f[2 * j + 1]);
        float h0f = __uint_as_float(h0 << 16);
        float h1f = __uint_as_float(h1 << 16);
        bh.u[j] = h0 | (h1 << 16);
        bl.u[j] = rne1(f[2 * j] - h0f) | (rne1(f[2 * j + 1] - h1f) << 16);
      }
#pragma unroll
      for (int m = 0; m < 4; ++m) acc[n][m] = __builtin_amdgcn_mfma_f32_16x16x32_bf16(ah[m], bh.v, acc[n][m], 0, 0, 0);
#pragma unroll
      for (int m = 0; m < 4; ++m) acc[n][m] = __builtin_amdgcn_mfma_f32_16x16x32_bf16(ah[m], bl.v, acc[n][m], 0, 0, 0);
#pragma unroll
      for (int m = 0; m < 4; ++m) acc[n][m] = __builtin_amdgcn_mfma_f32_16x16x32_bf16(al[m], bh.v, acc[n][m], 0, 0, 0);
    }
    __builtin_amdgcn_sched_barrier(0);

    // write next tile to the other buffer (b128; rows 1040 B apart -> 16B aligned)
    if (tt + 1 < 16) {
#pragma unroll
      for (int i = 0; i < 8; ++i) {
        const int r = w + 4 * i;
        *(f32x4*)&lds[buf ^ 1][r * 260 + 4 * l] = (f32x4)gg[i];
      }
    }
    __syncthreads();
  }

  float* pout = part2 + (size_t)blockIdx.y * ((size_t)64 * V_);
#pragma unroll
  for (int n = 0; n < 4; ++n) {
    const int c = c0 + w * 64 + n * 16 + col;
#pragma unroll
    for (int m = 0; m < 4; ++m)
#pragma unroll
      for (int i = 0; i < 4; ++i)
        pout[(size_t)(m * 16 + g * 4 + i) * V_ + c] = acc[n][m][i];
  }
}

// ---------------- softmax over rows (reads split-K partials + bias directly) -------------
#define SM_CHUNK 12565  // 4 * 12565 >= V_

__global__ void k_softmax1(const float* __restrict__ part2, const float* __restrict__ bs,
                           float2* __restrict__ stats) {
  __shared__ float smx[4], ssum[4];
  const int r = blockIdx.x >> 2, q = blockIdx.x & 3;
  const int beg = q * SM_CHUNK;
  const int end = (beg + SM_CHUNK < V_) ? beg + SM_CHUNK : V_;
  const float* p0 = part2 + (size_t)r * V_;
  const float* p1 = part2 + (size_t)64 * V_ + (size_t)r * V_;

  float mx = -3.4e38f;
  for (int i = beg + threadIdx.x; i < end; i += 256) mx = fmaxf(mx, p0[i] + p1[i] + bs[i]);
  mx = waveMax(mx);
  if ((threadIdx.x & 63) == 0) smx[threadIdx.x >> 6] = mx;
  __syncthreads();
  mx = fmaxf(fmaxf(smx[0], smx[1]), fmaxf(smx[2], smx[3]));

  float s = 0.f;
  for (int i = beg + threadIdx.x; i < end; i += 256) s += __expf(p0[i] + p1[i] + bs[i] - mx);
  s = waveSum(s);
  if ((threadIdx.x & 63) == 0) ssum[threadIdx.x >> 6] = s;
  __syncthreads();
  s = (ssum[0] + ssum[1]) + (ssum[2] + ssum[3]);

  if (threadIdx.x == 0) stats[blockIdx.x] = make_float2(mx, s);
}

__global__ void k_softmax2(const float* __restrict__ part2, const float* __restrict__ bs,
                           const float2* __restrict__ stats, float* __restrict__ out) {
  const int r = blockIdx.x >> 2, q = blockIdx.x & 3;
  float2 s0 = stats[r * 4 + 0], s1 = stats[r * 4 + 1];
  float2 s2 = stats[r * 4 + 2], s3 = stats[r * 4 + 3];
  float M = fmaxf(fmaxf(s0.x, s1.x), fmaxf(s2.x, s3.x));
  float S = s0.y * __expf(s0.x - M) + s1.y * __expf(s1.x - M)
          + s2.y * __expf(s2.x - M) + s3.y * __expf(s3.x - M);
  float inv = 1.f / S;
  const int beg = q * SM_CHUNK;
  const int end = (beg + SM_CHUNK < V_) ? beg + SM_CHUNK : V_;
  const float* p0 = part2 + (size_t)r * V_;
  const float* p1 = part2 + (size_t)64 * V_ + (size_t)r * V_;
  float* orow = out + (size_t)r * V_;
  for (int i = beg + threadIdx.x; i < end; i += 256)
    orow[i] = __expf(p0[i] + p1[i] + bs[i] - M) * inv;
}

// ---------------- launch ----------------
extern "C" void kernel_launch(void* const* d_in, const int* in_sizes, int n_in,
                              void* d_out, int out_size, void* d_ws, size_t ws_size,
                              hipStream_t stream) {
  const float* eh   = (const float*)d_in[0];
  const int*   ques = (const int*)d_in[1];
  const void*  mask = d_in[2];
  const float* emb  = (const float*)d_in[3];
  const float* W1   = (const float*)d_in[4];
  const float* b1   = (const float*)d_in[5];
  const float* W2   = (const float*)d_in[6];
  const float* b2   = (const float*)d_in[7];
  const float* A    = (const float*)d_in[8];
  const float* H    = (const float*)d_in[9];
  const float* Ws   = (const float*)d_in[10];
  const float* bs   = (const float*)d_in[11];
  float* out = (float*)d_out;
  char* ws = (char*)d_ws;

  // ws layout (bytes). gpart aliases the first region (temporally disjoint from part2 use).
  float*          gpart   = (float*)(ws + 0);           // max 8,388,608
  float*          entpart = (float*)(ws + 12866048);    // 2,097,152
  float*          entsum  = (float*)(ws + 14963200);    // 4,096
  float*          hbuf    = (float*)(ws + 14967296);    // 524,288
  float*          qbuf    = (float*)(ws + 15491584);    // 262,144
  float*          ubuf    = (float*)(ws + 15753728);    // 262,144
  unsigned short* zpkh    = (unsigned short*)(ws + 16015872);  // 131,072 (packed fragments)
  unsigned short* zpkl    = (unsigned short*)(ws + 16146944);  // 131,072
  float2*         stats   = (float2*)(ws + 16278016);   // 2,048
  float*          part2   = (float*)(ws + 20971520);    // 2*64*V*4 = 25,731,584

  // P1: ent_partial (512 blocks) || h-gemm partials (512 blocks)
  k_p1<<<1024, 256, 0, stream>>>(eh, mask, entpart, ques, emb, W1, gpart);
  // P2: ent_reduce (4) || h = relu(.+b1) (512)
  k_p2<<<516, 256, 0, stream>>>(entpart, entsum, gpart, b1, hbuf);

  // P3/P4: q = h @ W2 + b2                 [64,1024], K=2048, split 32
  k_gemm64<<<dim3(16, 32), 256, 0, stream>>>(hbuf, W2, 2048, 1024, 64, gpart);
  k_reduce_t<32><<<256, 256, 0, stream>>>(gpart, 64 * 1024, 1024, b2, nullptr, 2, qbuf, nullptr, nullptr);

  // P5/P6: u = (q @ A) * ent_sum           [64,1024], split 16
  k_gemm64<<<dim3(16, 16), 256, 0, stream>>>(qbuf, A, 1024, 1024, 64, gpart);
  k_reduce_t<16><<<256, 256, 0, stream>>>(gpart, 64 * 1024, 1024, entsum, nullptr, 3, ubuf, nullptr, nullptr);

  // P7/P8: z = q + u @ H -> zpack bf16 hi/lo (MFMA-fragment order), split 16
  k_gemm64<<<dim3(16, 16), 256, 0, stream>>>(ubuf, H, 1024, 1024, 64, gpart);
  k_reduce_t<16><<<256, 256, 0, stream>>>(gpart, 64 * 1024, 1024, nullptr, qbuf, 4, nullptr, zpkh, zpkl);

  // P9: split-K partials = z @ Ws          [64,V]x2, 256-col tiles, 394 blocks
  k_gemm_big<<<dim3(197, 2), 256, 0, stream>>>(zpkh, zpkl, Ws, part2);

  // P10/P11: softmax two-pass over (p0+p1+bs)
  k_softmax1<<<256, 256, 0, stream>>>(part2, bs, stats);
  k_softmax2<<<256, 256, 0, stream>>>(part2, bs, stats, out);

  (void)in_sizes; (void)n_in; (void)out_size; (void)ws_size;
}

// Round 15
// 250.999 us; speedup vs baseline: 1.3412x; 1.0060x over previous
//
#include <hip/hip_runtime.h>
#include <stdint.h>

#define V_ 50257
#define D_ 1024
#define F_ 2048
#define B_ 64
#define E_ 512
#define ROWS_ (B_*E_)

typedef __attribute__((ext_vector_type(8))) short bf16x8;
typedef __attribute__((ext_vector_type(4))) float f32x4;
typedef __attribute__((ext_vector_type(4), aligned(4))) float f32x4a;  // 4B-aligned global loads

__device__ __forceinline__ unsigned rne1(float a) {
  unsigned u = __float_as_uint(a);
  return (u + 0x7FFFu + ((u >> 16) & 1u)) >> 16;
}

__device__ __forceinline__ float waveMax(float v) {
#pragma unroll
  for (int o = 32; o > 0; o >>= 1) v = fmaxf(v, __shfl_xor(v, o, 64));
  return v;
}
__device__ __forceinline__ float waveSum(float v) {
#pragma unroll
  for (int o = 32; o > 0; o >>= 1) v += __shfl_xor(v, o, 64);
  return v;
}

// ---------------- device bodies ----------------

__device__ __forceinline__ void ent_partial_body(int bid, const float* __restrict__ eh,
                                                 const void* __restrict__ mask,
                                                 float* __restrict__ part) {
  __shared__ int s_mode;
  const int tid = threadIdx.x;
  const uint32_t* mu = (const uint32_t*)mask;
  int f = 0;
  for (int i = tid; i < (ROWS_ / 4); i += 256) {
    uint32_t u = mu[i];
    if (u == 0x3F800000u) f |= 2;
    else if (u & 0xFFFFFF00u) f |= 1;
  }
  if (tid == 0) s_mode = 0;
  __syncthreads();
  if (f) atomicOr(&s_mode, f);
  __syncthreads();
  const int sm = s_mode;
  const int mode = (sm & 1) ? 1 : ((sm & 2) ? 2 : 0);

  float4 acc = make_float4(0.f, 0.f, 0.f, 0.f);
  const float4* eh4 = (const float4*)eh;
  for (int row = bid; row < ROWS_; row += 512) {
    bool on;
    if (mode == 1)      on = ((const unsigned char*)mask)[row] != 0;
    else if (mode == 2) on = ((const float*)mask)[row] != 0.f;
    else                on = ((const int*)mask)[row] != 0;
    if (on) {
      float4 v = eh4[(size_t)row * (D_ / 4) + tid];
      acc.x += v.x; acc.y += v.y; acc.z += v.z; acc.w += v.w;
    }
  }
  ((float4*)part)[(size_t)bid * (D_ / 4) + tid] = acc;
}

__device__ __forceinline__ void ent_reduce_body(int bid, const float* __restrict__ part,
                                                float* __restrict__ entsum) {
  int d = bid * 256 + threadIdx.x;
  float s0 = 0.f, s1 = 0.f, s2 = 0.f, s3 = 0.f;
#pragma unroll 8
  for (int i = 0; i < 512; i += 4) {
    s0 += part[(size_t)(i    ) * D_ + d];
    s1 += part[(size_t)(i + 1) * D_ + d];
    s2 += part[(size_t)(i + 2) * D_ + d];
    s3 += part[(size_t)(i + 3) * D_ + d];
  }
  entsum[d] = (s0 + s1) + (s2 + s3);
}

__device__ __forceinline__ void gemm64_body(int bx, int by, const float* __restrict__ X,
                                            const int* __restrict__ gatherIdx,
                                            const float* __restrict__ emb,
                                            const float* __restrict__ W,
                                            int K, int N, int KB, float* __restrict__ part) {
  const int l  = threadIdx.x & 63;
  const int rg = __builtin_amdgcn_readfirstlane((int)(threadIdx.x >> 6));
  const int c  = bx * 64 + l;
  const int k0 = by * KB;
  const int m0 = rg * 16;

  const float* Xp = gatherIdx ? emb : X;
  int rb[16];
#pragma unroll
  for (int r = 0; r < 16; ++r) {
    int m = m0 + r;
    rb[r] = gatherIdx ? gatherIdx[m] * K : m * K;
  }

  float acc[16];
#pragma unroll
  for (int r = 0; r < 16; ++r) acc[r] = 0.f;

  for (int k = k0; k < k0 + KB; k += 8) {
    float wv[8];
#pragma unroll
    for (int j = 0; j < 8; ++j) wv[j] = W[(size_t)(k + j) * N + c];
#pragma unroll
    for (int r = 0; r < 16; ++r) {
      float4 x0 = *(const float4*)&Xp[rb[r] + k];
      float4 x1 = *(const float4*)&Xp[rb[r] + k + 4];
      acc[r] = fmaf(x0.x, wv[0], acc[r]);
      acc[r] = fmaf(x0.y, wv[1], acc[r]);
      acc[r] = fmaf(x0.z, wv[2], acc[r]);
      acc[r] = fmaf(x0.w, wv[3], acc[r]);
      acc[r] = fmaf(x1.x, wv[4], acc[r]);
      acc[r] = fmaf(x1.y, wv[5], acc[r]);
      acc[r] = fmaf(x1.z, wv[6], acc[r]);
      acc[r] = fmaf(x1.w, wv[7], acc[r]);
    }
  }
  size_t base = (size_t)by * ((size_t)64 * N);
#pragma unroll
  for (int r = 0; r < 16; ++r) part[base + (size_t)(m0 + r) * N + c] = acc[r];
}

// reduce split-K partials + epilogue, compile-time NSPLIT (all loads issue in parallel).
// mode 1: relu(x+vecB[c]); 2: x+vecB[c]; 3: x*vecB[c];
// mode 4: idx is the zpack DEST index; gathers src, writes bf16 hi/lo in MFMA-fragment order.
template<int NSPLIT>
__device__ __forceinline__ void reduce_body_t(int bid, const float* __restrict__ part,
                                              int MN, int N,
                                              const float* __restrict__ vecB,
                                              const float* __restrict__ addend,
                                              int mode, float* __restrict__ dst,
                                              unsigned short* __restrict__ ph,
                                              unsigned short* __restrict__ pl) {
  int idx = bid * 256 + threadIdx.x;
  if (idx >= MN) return;

  if (mode == 4) {
    // dest-indexed zpack: d -> (tg, m, l, j) -> src element (row, kk)
    const int d   = idx;
    const int j   = d & 7;
    const int l   = (d >> 3) & 63;
    const int m   = (d >> 9) & 3;
    const int tg  = d >> 11;
    const int col = l & 15;
    const int g   = l >> 4;
    const int row = m * 16 + col;
    const int kk  = tg * 32 + g * 8 + j;
    const int src = row * 1024 + kk;
    float s = 0.f;
#pragma unroll
    for (int i = 0; i < NSPLIT; ++i) s += part[(size_t)i * MN + src];
    s += addend[src];
    unsigned hi = rne1(s);
    float hif = __uint_as_float(hi << 16);
    ph[d] = (unsigned short)hi;
    pl[d] = (unsigned short)rne1(s - hif);
    return;
  }

  float s = 0.f;
#pragma unroll
  for (int i = 0; i < NSPLIT; ++i) s += part[(size_t)i * MN + idx];
  int c = idx & (N - 1);
  if (mode == 1)      { s += vecB[c]; s = s > 0.f ? s : 0.f; dst[idx] = s; }
  else if (mode == 2) { s += vecB[c]; dst[idx] = s; }
  else                { s *= vecB[c]; dst[idx] = s; }
}

// ---------------- fused phase kernels ----------------
__global__ void k_p1(const float* __restrict__ eh, const void* __restrict__ mask,
                     float* __restrict__ entpart, const int* __restrict__ ques,
                     const float* __restrict__ emb, const float* __restrict__ W1,
                     float* __restrict__ gpart) {
  int bid = blockIdx.x;
  if (bid < 512) ent_partial_body(bid, eh, mask, entpart);
  else {
    int b2 = bid - 512;
    gemm64_body(b2 & 31, b2 >> 5, nullptr, ques, emb, W1, 1024, 2048, 64, gpart);
  }
}

__global__ void k_p2(const float* __restrict__ entpart, float* __restrict__ entsum,
                     const float* __restrict__ gpart, const float* __restrict__ b1,
                     float* __restrict__ hbuf) {
  int bid = blockIdx.x;
  if (bid < 4) ent_reduce_body(bid, entpart, entsum);
  else reduce_body_t<16>(bid - 4, gpart, 64 * 2048, 2048, b1, nullptr, 1, hbuf, nullptr, nullptr);
}

__global__ void k_gemm64(const float* __restrict__ X, const float* __restrict__ W,
                         int K, int N, int KB, float* __restrict__ part) {
  gemm64_body(blockIdx.x, blockIdx.y, X, nullptr, nullptr, W, K, N, KB, part);
}

template<int NSPLIT>
__global__ void k_reduce_t(const float* __restrict__ part, int MN, int N,
                           const float* __restrict__ vecB, const float* __restrict__ addend,
                           int mode, float* __restrict__ dst,
                           unsigned short* __restrict__ ph, unsigned short* __restrict__ pl) {
  reduce_body_t<NSPLIT>(blockIdx.x, part, MN, N, vecB, addend, mode, dst, ph, pl);
}

// ---------------- big GEMM: split-K partials, 256-col tiles, split-bf16 MFMA -------------
// Round-14: (197 col-blocks x 2 K-halves) = 394 blocks -> all 256 CUs busy (was 198 at
// 1/CU; m13's 24.6 GB/s/CU makes CU coverage the floor-setter). LDS 2 x 32x260 f32 =
// 66.5 KB -> 2 blocks/CU resident. z-fragments come from zpack (pre-packed in per-lane
// MFMA order by the mode-4 epilogue): every z load is a fully coalesced 1 KB wave
// instruction (was 16 x 64 B scatter). Staging keeps the round-13 reg-staged f32x4 +
// ds_write_b128 + sched_barrier discipline. Tail col-block shifts c0 to V-256 (overlap
// cols written twice with identical values - benign, round-13 precedent).
__global__ __launch_bounds__(256, 2) void k_gemm_big(const unsigned short* __restrict__ zpkh,
                                                     const unsigned short* __restrict__ zpkl,
                                                     const float* __restrict__ Ws,
                                                     float* __restrict__ part2) {
  __shared__ float lds[2][32 * 260];   // 66,560 B
  const int t   = threadIdx.x;
  const int l   = t & 63;
  const int w   = t >> 6;              // wave 0..3
  const int col = l & 15;
  const int g   = l >> 4;              // k-chunk g*8..g*8+7
  const int c0  = (blockIdx.x < 196) ? blockIdx.x * 256 : (V_ - 256);
  const int kbase = blockIdx.y * 512;

  f32x4 acc[4][4];  // [n][m]
#pragma unroll
  for (int n = 0; n < 4; ++n)
#pragma unroll
    for (int m = 0; m < 4; ++m) acc[n][m] = (f32x4){0.f, 0.f, 0.f, 0.f};

  // prologue: stage tile 0. wave w stages rows w+4i (i=0..7); lane covers cols 4l..4l+3.
  {
    f32x4a gg[8];
#pragma unroll
    for (int i = 0; i < 8; ++i) {
      const int r = w + 4 * i;
      gg[i] = *(const f32x4a*)(Ws + (size_t)(kbase + r) * V_ + c0 + 4 * l);
    }
#pragma unroll
    for (int i = 0; i < 8; ++i) {
      const int r = w + 4 * i;
      *(f32x4*)&lds[0][r * 260 + 4 * l] = (f32x4)gg[i];
    }
  }
  __syncthreads();

  for (int tt = 0; tt < 16; ++tt) {
    const int buf = tt & 1;
    const int tg  = (kbase >> 5) + tt;

    // z-fragments first (oldest): coalesced 16B/lane from zpack; compute's wait for them
    // (counted vmcnt) leaves the Ws loads in flight.
    bf16x8 ah[4], al[4];
#pragma unroll
    for (int m = 0; m < 4; ++m) {
      const int zb = ((tg * 4 + m) * 64 + l) * 8;
      ah[m] = *(const bf16x8*)(zpkh + zb);
      al[m] = *(const bf16x8*)(zpkl + zb);
    }

    // next Ws tile -> registers (1 KB contiguous per wave-instruction)
    f32x4a gg[8];
    if (tt + 1 < 16) {
      const float* wb = Ws + (size_t)(kbase + (tt + 1) * 32) * V_ + c0 + 4 * l;
#pragma unroll
      for (int i = 0; i < 8; ++i)
        gg[i] = *(const f32x4a*)(wb + (size_t)(w + 4 * i) * V_);
    }
    __builtin_amdgcn_sched_barrier(0);

    // compute tile tt from lds[buf]
#pragma unroll
    for (int n = 0; n < 4; ++n) {
      float f[8];
#pragma unroll
      for (int j = 0; j < 8; ++j)
        f[j] = lds[buf][(g * 8 + j) * 260 + w * 64 + n * 16 + col];

      union { bf16x8 v; unsigned u[4]; } bh, bl;
#pragma unroll
      for (int j = 0; j < 4; ++j) {
        unsigned h0 = rne1(f[2 * j]);
        unsigned h1 = rne1(f[2 * j + 1]);
        float h0f = __uint_as_float(h0 << 16);
        float h1f = __uint_as_float(h1 << 16);
        bh.u[j] = h0 | (h1 << 16);
        bl.u[j] = rne1(f[2 * j] - h0f) | (rne1(f[2 * j + 1] - h1f) << 16);
      }
#pragma unroll
      for (int m = 0; m < 4; ++m) acc[n][m] = __builtin_amdgcn_mfma_f32_16x16x32_bf16(ah[m], bh.v, acc[n][m], 0, 0, 0);
#pragma unroll
      for (int m = 0; m < 4; ++m) acc[n][m] = __builtin_amdgcn_mfma_f32_16x16x32_bf16(ah[m], bl.v, acc[n][m], 0, 0, 0);
#pragma unroll
      for (int m = 0; m < 4; ++m) acc[n][m] = __builtin_amdgcn_mfma_f32_16x16x32_bf16(al[m], bh.v, acc[n][m], 0, 0, 0);
    }
    __builtin_amdgcn_sched_barrier(0);

    // write next tile to the other buffer (b128; rows 1040 B apart -> 16B aligned)
    if (tt + 1 < 16) {
#pragma unroll
      for (int i = 0; i < 8; ++i) {
        const int r = w + 4 * i;
        *(f32x4*)&lds[buf ^ 1][r * 260 + 4 * l] = (f32x4)gg[i];
      }
    }
    __syncthreads();
  }

  float* pout = part2 + (size_t)blockIdx.y * ((size_t)64 * V_);
#pragma unroll
  for (int n = 0; n < 4; ++n) {
    const int c = c0 + w * 64 + n * 16 + col;
#pragma unroll
    for (int m = 0; m < 4; ++m)
#pragma unroll
      for (int i = 0; i < 4; ++i)
        pout[(size_t)(m * 16 + g * 4 + i) * V_ + c] = acc[n][m][i];
  }
}

// ---------------- softmax over rows (reads split-K partials + bias directly) -------------
#define SM_CHUNK 12565  // 4 * 12565 >= V_

__global__ void k_softmax1(const float* __restrict__ part2, const float* __restrict__ bs,
                           float2* __restrict__ stats) {
  __shared__ float smx[4], ssum[4];
  const int r = blockIdx.x >> 2, q = blockIdx.x & 3;
  const int beg = q * SM_CHUNK;
  const int end = (beg + SM_CHUNK < V_) ? beg + SM_CHUNK : V_;
  const float* p0 = part2 + (size_t)r * V_;
  const float* p1 = part2 + (size_t)64 * V_ + (size_t)r * V_;

  float mx = -3.4e38f;
  for (int i = beg + threadIdx.x; i < end; i += 256) mx = fmaxf(mx, p0[i] + p1[i] + bs[i]);
  mx = waveMax(mx);
  if ((threadIdx.x & 63) == 0) smx[threadIdx.x >> 6] = mx;
  __syncthreads();
  mx = fmaxf(fmaxf(smx[0], smx[1]), fmaxf(smx[2], smx[3]));

  float s = 0.f;
  for (int i = beg + threadIdx.x; i < end; i += 256) s += __expf(p0[i] + p1[i] + bs[i] - mx);
  s = waveSum(s);
  if ((threadIdx.x & 63) == 0) ssum[threadIdx.x >> 6] = s;
  __syncthreads();
  s = (ssum[0] + ssum[1]) + (ssum[2] + ssum[3]);

  if (threadIdx.x == 0) stats[blockIdx.x] = make_float2(mx, s);
}

__global__ void k_softmax2(const float* __restrict__ part2, const float* __restrict__ bs,
                           const float2* __restrict__ stats, float* __restrict__ out) {
  const int r = blockIdx.x >> 2, q = blockIdx.x & 3;
  float2 s0 = stats[r * 4 + 0], s1 = stats[r * 4 + 1];
  float2 s2 = stats[r * 4 + 2], s3 = stats[r * 4 + 3];
  float M = fmaxf(fmaxf(s0.x, s1.x), fmaxf(s2.x, s3.x));
  float S = s0.y * __expf(s0.x - M) + s1.y * __expf(s1.x - M)
          + s2.y * __expf(s2.x - M) + s3.y * __expf(s3.x - M);
  float inv = 1.f / S;
  const int beg = q * SM_CHUNK;
  const int end = (beg + SM_CHUNK < V_) ? beg + SM_CHUNK : V_;
  const float* p0 = part2 + (size_t)r * V_;
  const float* p1 = part2 + (size_t)64 * V_ + (size_t)r * V_;
  float* orow = out + (size_t)r * V_;
  for (int i = beg + threadIdx.x; i < end; i += 256)
    orow[i] = __expf(p0[i] + p1[i] + bs[i] - M) * inv;
}

// ---------------- launch ----------------
extern "C" void kernel_launch(void* const* d_in, const int* in_sizes, int n_in,
                              void* d_out, int out_size, void* d_ws, size_t ws_size,
                              hipStream_t stream) {
  const float* eh   = (const float*)d_in[0];
  const int*   ques = (const int*)d_in[1];
  const void*  mask = d_in[2];
  const float* emb  = (const float*)d_in[3];
  const float* W1   = (const float*)d_in[4];
  const float* b1   = (const float*)d_in[5];
  const float* W2   = (const float*)d_in[6];
  const float* b2   = (const float*)d_in[7];
  const float* A    = (const float*)d_in[8];
  const float* H    = (const float*)d_in[9];
  const float* Ws   = (const float*)d_in[10];
  const float* bs   = (const float*)d_in[11];
  float* out = (float*)d_out;
  char* ws = (char*)d_ws;

  // ws layout (bytes). gpart aliases the first region (temporally disjoint from part2 use).
  float*          gpart   = (float*)(ws + 0);           // max 8,388,608
  float*          entpart = (float*)(ws + 12866048);    // 2,097,152
  float*          entsum  = (float*)(ws + 14963200);    // 4,096
  float*          hbuf    = (float*)(ws + 14967296);    // 524,288
  float*          qbuf    = (float*)(ws + 15491584);    // 262,144
  float*          ubuf    = (float*)(ws + 15753728);    // 262,144
  unsigned short* zpkh    = (unsigned short*)(ws + 16015872);  // 131,072 (packed fragments)
  unsigned short* zpkl    = (unsigned short*)(ws + 16146944);  // 131,072
  float2*         stats   = (float2*)(ws + 16278016);   // 2,048
  float*          part2   = (float*)(ws + 20971520);    // 2*64*V*4 = 25,731,584

  // P1: ent_partial (512 blocks) || h-gemm partials (512 blocks)
  k_p1<<<1024, 256, 0, stream>>>(eh, mask, entpart, ques, emb, W1, gpart);
  // P2: ent_reduce (4) || h = relu(.+b1) (512)
  k_p2<<<516, 256, 0, stream>>>(entpart, entsum, gpart, b1, hbuf);

  // P3/P4: q = h @ W2 + b2                 [64,1024], K=2048, split 32
  k_gemm64<<<dim3(16, 32), 256, 0, stream>>>(hbuf, W2, 2048, 1024, 64, gpart);
  k_reduce_t<32><<<256, 256, 0, stream>>>(gpart, 64 * 1024, 1024, b2, nullptr, 2, qbuf, nullptr, nullptr);

  // P5/P6: u = (q @ A) * ent_sum           [64,1024], split 16
  k_gemm64<<<dim3(16, 16), 256, 0, stream>>>(qbuf, A, 1024, 1024, 64, gpart);
  k_reduce_t<16><<<256, 256, 0, stream>>>(gpart, 64 * 1024, 1024, entsum, nullptr, 3, ubuf, nullptr, nullptr);

  // P7/P8: z = q + u @ H -> zpack bf16 hi/lo (MFMA-fragment order), split 16
  k_gemm64<<<dim3(16, 16), 256, 0, stream>>>(ubuf, H, 1024, 1024, 64, gpart);
  k_reduce_t<16><<<256, 256, 0, stream>>>(gpart, 64 * 1024, 1024, nullptr, qbuf, 4, nullptr, zpkh, zpkl);

  // P9: split-K partials = z @ Ws          [64,V]x2, 256-col tiles, 394 blocks
  k_gemm_big<<<dim3(197, 2), 256, 0, stream>>>(zpkh, zpkl, Ws, part2);

  // P10/P11: softmax two-pass over (p0+p1+bs)
  k_softmax1<<<256, 256, 0, stream>>>(part2, bs, stats);
  k_softmax2<<<256, 256, 0, stream>>>(part2, bs, stats, out);

  (void)in_sizes; (void)n_in; (void)out_size; (void)ws_size;
}